// Round 1
// baseline (1982.329 us; speedup 1.0000x reference)
//
#include <hip/hip_runtime.h>
#include <cstdint>

#define NEG_SLOPE 0.2f

// ---------------- CSR build ----------------

__global__ __launch_bounds__(256) void hist_kernel(const int* __restrict__ ei,
                                                   int* __restrict__ deg, int E, int N) {
  int e = blockIdx.x * 256 + threadIdx.x;
  int total = E + N;
  if (e >= total) return;
  int d = (e < E) ? ei[E + e] : (e - E);   // self-loop for virtual edges
  atomicAdd(&deg[d], 1);
}

__global__ __launch_bounds__(1024) void scan_kernel(const int* __restrict__ deg,
                                                    int* __restrict__ rowstart,
                                                    int* __restrict__ cursor, int n) {
  __shared__ int sums[1024];
  int tid = threadIdx.x;
  int chunk = (n + 1023) / 1024;
  int start = tid * chunk;
  if (start > n) start = n;
  int end = start + chunk;
  if (end > n) end = n;
  int s = 0;
  for (int i = start; i < end; i++) s += deg[i];
  sums[tid] = s;
  __syncthreads();
  for (int off = 1; off < 1024; off <<= 1) {
    int v = (tid >= off) ? sums[tid - off] : 0;
    __syncthreads();
    sums[tid] += v;
    __syncthreads();
  }
  int base = (tid == 0) ? 0 : sums[tid - 1];
  for (int i = start; i < end; i++) {
    rowstart[i] = base;
    cursor[i] = base;
    base += deg[i];
  }
  if (tid == 0) rowstart[n] = sums[1023];
}

__global__ __launch_bounds__(256) void scatter_kernel(const int* __restrict__ ei,
                                                      int* __restrict__ cursor,
                                                      int* __restrict__ csr_src, int E, int N) {
  int e = blockIdx.x * 256 + threadIdx.x;
  int total = E + N;
  if (e >= total) return;
  int s, d;
  if (e < E) { s = ei[e]; d = ei[E + e]; }
  else       { s = e - E; d = e - E; }
  int p = atomicAdd(&cursor[d], 1);
  csr_src[p] = s;
}

// ---------------- fp32 tiled GEMM (BM=128, BN=64, BK=16, 8x4 microtile) ----------------

__global__ __launch_bounds__(256) void sgemm128(const float* __restrict__ A,
                                                const float* __restrict__ B,
                                                float* __restrict__ C,
                                                int M, int N, int K) {
  __shared__ float As[16][129];  // As[k][m], +1 pad
  __shared__ float Bs[16][64];
  int bm = blockIdx.x * 128;
  int bn = blockIdx.y * 64;
  int tid = threadIdx.x;
  int tx = tid & 15, ty = tid >> 4;
  float acc[8][4];
#pragma unroll
  for (int i = 0; i < 8; i++)
#pragma unroll
    for (int j = 0; j < 4; j++) acc[i][j] = 0.f;

  for (int k0 = 0; k0 < K; k0 += 16) {
#pragma unroll
    for (int i = 0; i < 8; i++) {
      int idx = tid + i * 256;
      int r = idx >> 4, c = idx & 15;
      int row = bm + r;
      float v = 0.f;
      if (row < M) v = A[(int64_t)row * K + k0 + c];
      As[c][r] = v;
    }
#pragma unroll
    for (int i = 0; i < 4; i++) {
      int idx = tid + i * 256;
      int r = idx >> 6, c = idx & 63;
      Bs[r][c] = B[(int64_t)(k0 + r) * N + bn + c];
    }
    __syncthreads();
#pragma unroll
    for (int kk = 0; kk < 16; kk++) {
      float a[8], b[4];
#pragma unroll
      for (int u = 0; u < 8; u++) a[u] = As[kk][ty * 8 + u];
#pragma unroll
      for (int u = 0; u < 4; u++) b[u] = Bs[kk][tx * 4 + u];
#pragma unroll
      for (int i = 0; i < 8; i++)
#pragma unroll
        for (int j = 0; j < 4; j++) acc[i][j] += a[i] * b[j];
    }
    __syncthreads();
  }
#pragma unroll
  for (int i = 0; i < 8; i++) {
    int row = bm + ty * 8 + i;
    if (row < M) {
#pragma unroll
      for (int j = 0; j < 4; j++)
        C[(int64_t)row * N + bn + tx * 4 + j] = acc[i][j];
    }
  }
}

// ---------------- alpha dot products: as[n]=h[n]·a_src, ad[n]=h[n]·a_dst ----------------

__global__ __launch_bounds__(256) void alpha_kernel(const float* __restrict__ h,
                                                    const float* __restrict__ a_s,
                                                    const float* __restrict__ a_d,
                                                    float* __restrict__ as_,
                                                    float* __restrict__ ad_,
                                                    int N, int F) {
  int wid = (blockIdx.x * 256 + threadIdx.x) >> 6;
  int lane = threadIdx.x & 63;
  if (wid >= N) return;
  float ss = 0.f, dd = 0.f;
  for (int c = lane; c < F; c += 64) {
    float v = h[(int64_t)wid * F + c];
    ss += v * a_s[c];
    dd += v * a_d[c];
  }
#pragma unroll
  for (int off = 32; off; off >>= 1) {
    ss += __shfl_down(ss, off);
    dd += __shfl_down(dd, off);
  }
  if (lane == 0) { as_[wid] = ss; ad_[wid] = dd; }
}

// ---------------- per-node edge softmax + aggregate + bias (+relu) ----------------
// one 64-lane wave per destination node; lanes own feature columns (VPL each)

template <int VPL>
__global__ __launch_bounds__(256) void agg_kernel(const float* __restrict__ h,
                                                  const float* __restrict__ as_,
                                                  const float* __restrict__ ad_,
                                                  const int* __restrict__ rowstart,
                                                  const int* __restrict__ csr_src,
                                                  const float* __restrict__ bias,
                                                  float* __restrict__ out,
                                                  int N, int F, int do_relu) {
  int wid = (blockIdx.x * 256 + threadIdx.x) >> 6;
  int lane = threadIdx.x & 63;
  if (wid >= N) return;
  int r0 = rowstart[wid], r1 = rowstart[wid + 1];
  float adn = ad_[wid];

  // pass 1: segment max
  float m = -1e30f;
  for (int i = r0 + lane; i < r1; i += 64) {
    float e = as_[csr_src[i]] + adn;
    e = e > 0.f ? e : NEG_SLOPE * e;
    m = fmaxf(m, e);
  }
#pragma unroll
  for (int off = 32; off; off >>= 1) m = fmaxf(m, __shfl_xor(m, off));

  // pass 2: segment sum of exp
  float ssum = 0.f;
  for (int i = r0 + lane; i < r1; i += 64) {
    float e = as_[csr_src[i]] + adn;
    e = e > 0.f ? e : NEG_SLOPE * e;
    ssum += __expf(e - m);
  }
#pragma unroll
  for (int off = 32; off; off >>= 1) ssum += __shfl_xor(ssum, off);
  float inv = 1.f / ssum;

  // pass 3: weighted aggregate; all lanes walk edges together, lane owns columns
  float acc[VPL];
#pragma unroll
  for (int v = 0; v < VPL; v++) acc[v] = 0.f;
  for (int k = r0; k < r1; k++) {
    int s = csr_src[k];  // wave-uniform -> broadcast load
    float e = as_[s] + adn;
    e = e > 0.f ? e : NEG_SLOPE * e;
    float w = __expf(e - m);
    const float* hrow = h + (int64_t)s * F;
#pragma unroll
    for (int v = 0; v < VPL; v++) acc[v] += w * hrow[lane + v * 64];
  }
#pragma unroll
  for (int v = 0; v < VPL; v++) {
    int c = lane + v * 64;
    float o = acc[v] * inv + bias[c];
    if (do_relu) o = fmaxf(o, 0.f);
    out[(int64_t)wid * F + c] = o;
  }
}

// ---------------- layer 3: GEMM (K x 2) + alpha3, wave per row ----------------

__global__ __launch_bounds__(256) void gemm3_kernel(const float* __restrict__ h,
                                                    const float* __restrict__ W3,
                                                    const float* __restrict__ a3s,
                                                    const float* __restrict__ a3d,
                                                    float* __restrict__ h3,
                                                    float* __restrict__ as_,
                                                    float* __restrict__ ad_,
                                                    int N, int K) {
  int wid = (blockIdx.x * 256 + threadIdx.x) >> 6;
  int lane = threadIdx.x & 63;
  if (wid >= N) return;
  float c0 = 0.f, c1 = 0.f;
  for (int k = lane; k < K; k += 64) {
    float v = h[(int64_t)wid * K + k];
    c0 += v * W3[k * 2 + 0];
    c1 += v * W3[k * 2 + 1];
  }
#pragma unroll
  for (int off = 32; off; off >>= 1) {
    c0 += __shfl_down(c0, off);
    c1 += __shfl_down(c1, off);
  }
  if (lane == 0) {
    h3[wid * 2 + 0] = c0;
    h3[wid * 2 + 1] = c1;
    as_[wid] = c0 * a3s[0] + c1 * a3s[1];
    ad_[wid] = c0 * a3d[0] + c1 * a3d[1];
  }
}

// ---------------- layer 3 aggregate + bias + final 2-class softmax ----------------

__global__ __launch_bounds__(256) void agg3_kernel(const float* __restrict__ h3,
                                                   const float* __restrict__ as_,
                                                   const float* __restrict__ ad_,
                                                   const int* __restrict__ rowstart,
                                                   const int* __restrict__ csr_src,
                                                   const float* __restrict__ b3,
                                                   float* __restrict__ out, int N) {
  int wid = (blockIdx.x * 256 + threadIdx.x) >> 6;
  int lane = threadIdx.x & 63;
  if (wid >= N) return;
  int r0 = rowstart[wid], r1 = rowstart[wid + 1];
  float adn = ad_[wid];

  float m = -1e30f;
  for (int i = r0 + lane; i < r1; i += 64) {
    float e = as_[csr_src[i]] + adn;
    e = e > 0.f ? e : NEG_SLOPE * e;
    m = fmaxf(m, e);
  }
#pragma unroll
  for (int off = 32; off; off >>= 1) m = fmaxf(m, __shfl_xor(m, off));

  float ssum = 0.f, a0 = 0.f, a1 = 0.f;
  for (int i = r0 + lane; i < r1; i += 64) {
    int s = csr_src[i];
    float e = as_[s] + adn;
    e = e > 0.f ? e : NEG_SLOPE * e;
    float w = __expf(e - m);
    ssum += w;
    a0 += w * h3[s * 2 + 0];
    a1 += w * h3[s * 2 + 1];
  }
#pragma unroll
  for (int off = 32; off; off >>= 1) {
    ssum += __shfl_xor(ssum, off);
    a0 += __shfl_xor(a0, off);
    a1 += __shfl_xor(a1, off);
  }
  if (lane == 0) {
    float inv = 1.f / ssum;
    float o0 = a0 * inv + b3[0];
    float o1 = a1 * inv + b3[1];
    float mm = fmaxf(o0, o1);
    float e0 = __expf(o0 - mm), e1 = __expf(o1 - mm);
    float d = e0 + e1;
    out[wid * 2 + 0] = e0 / d;
    out[wid * 2 + 1] = e1 / d;
  }
}

// ---------------- launcher ----------------

extern "C" void kernel_launch(void* const* d_in, const int* in_sizes, int n_in,
                              void* d_out, int out_size, void* d_ws, size_t ws_size,
                              hipStream_t stream) {
  const float* x   = (const float*)d_in[0];
  const int*   ei  = (const int*)d_in[1];
  // d_in[2] = batch (unused)
  const float* W1  = (const float*)d_in[3];
  const float* a1s = (const float*)d_in[4];
  const float* a1d = (const float*)d_in[5];
  const float* b1  = (const float*)d_in[6];
  const float* W2  = (const float*)d_in[7];
  const float* a2s = (const float*)d_in[8];
  const float* a2d = (const float*)d_in[9];
  const float* b2  = (const float*)d_in[10];
  const float* W3  = (const float*)d_in[11];
  const float* a3s = (const float*)d_in[12];
  const float* a3d = (const float*)d_in[13];
  const float* b3  = (const float*)d_in[14];

  int N   = in_sizes[2];
  int E   = in_sizes[1] / 2;
  int FIN = in_sizes[0] / N;
  int d1  = in_sizes[4];   // 128
  int d2  = in_sizes[8];   // 256

  // workspace carve
  char* p = (char*)d_ws;
  float* buf1 = (float*)p; p += (size_t)N * d2 * sizeof(float);   // h1 then h2
  float* buf2 = (float*)p; p += (size_t)N * d2 * sizeof(float);   // o1 then o2
  float* h3   = (float*)p; p += (size_t)N * 2 * sizeof(float);
  float* as_  = (float*)p; p += (size_t)N * sizeof(float);
  float* ad_  = (float*)p; p += (size_t)N * sizeof(float);
  int* deg      = (int*)p; p += (size_t)N * sizeof(int);
  int* rowstart = (int*)p; p += (size_t)(N + 1) * sizeof(int);
  int* cursor   = (int*)p; p += (size_t)N * sizeof(int);
  int* csr      = (int*)p; p += (size_t)(E + N) * sizeof(int);

  // CSR build
  hipMemsetAsync(deg, 0, (size_t)N * sizeof(int), stream);
  int tot = E + N;
  hist_kernel<<<(tot + 255) / 256, 256, 0, stream>>>(ei, deg, E, N);
  scan_kernel<<<1, 1024, 0, stream>>>(deg, rowstart, cursor, N);
  scatter_kernel<<<(tot + 255) / 256, 256, 0, stream>>>(ei, cursor, csr, E, N);

  int wb = (N + 3) / 4;  // wave-per-node, 4 waves/block

  // layer 1: x@W1 -> buf1 [N,128]; agg -> buf2 (relu)
  {
    dim3 g((N + 127) / 128, d1 / 64);
    sgemm128<<<g, 256, 0, stream>>>(x, W1, buf1, N, d1, FIN);
    alpha_kernel<<<wb, 256, 0, stream>>>(buf1, a1s, a1d, as_, ad_, N, d1);
    agg_kernel<2><<<wb, 256, 0, stream>>>(buf1, as_, ad_, rowstart, csr, b1, buf2, N, d1, 1);
  }
  // layer 2: buf2@W2 -> buf1 [N,256]; agg -> buf2 (relu)
  {
    dim3 g((N + 127) / 128, d2 / 64);
    sgemm128<<<g, 256, 0, stream>>>(buf2, W2, buf1, N, d2, d1);
    alpha_kernel<<<wb, 256, 0, stream>>>(buf1, a2s, a2d, as_, ad_, N, d2);
    agg_kernel<4><<<wb, 256, 0, stream>>>(buf1, as_, ad_, rowstart, csr, b2, buf2, N, d2, 1);
  }
  // layer 3: buf2@W3 -> h3 [N,2]; agg + bias + softmax -> d_out
  {
    gemm3_kernel<<<wb, 256, 0, stream>>>(buf2, W3, a3s, a3d, h3, as_, ad_, N, d2);
    agg3_kernel<<<wb, 256, 0, stream>>>(h3, as_, ad_, rowstart, csr, b3, (float*)d_out, N);
  }
}

// Round 2
// 1518.513 us; speedup vs baseline: 1.3054x; 1.3054x over previous
//
#include <hip/hip_runtime.h>
#include <cstdint>

#define NEG_SLOPE 0.2f

typedef __attribute__((ext_vector_type(8))) short short8;     // 8 bf16 = 4 VGPRs (guide §3)
typedef __attribute__((ext_vector_type(4))) float f32x4;

// split fp32 v into bf16 hi + bf16 lo (truncation; hi+lo ~ v to ~2^-16 rel)
__device__ inline void split_bf16(float v, short& hi, short& lo) {
  unsigned u = __builtin_bit_cast(unsigned, v);
  hi = (short)(u >> 16);
  float hif = __builtin_bit_cast(float, u & 0xffff0000u);
  float r = v - hif;
  lo = (short)(__builtin_bit_cast(unsigned, r) >> 16);
}

// ---------------- CSR build ----------------

__global__ __launch_bounds__(256) void hist_kernel(const int* __restrict__ ei,
                                                   int* __restrict__ deg, int E, int N) {
  int e = blockIdx.x * 256 + threadIdx.x;
  int total = E + N;
  if (e >= total) return;
  int d = (e < E) ? ei[E + e] : (e - E);   // self-loop for virtual edges
  atomicAdd(&deg[d], 1);
}

__global__ __launch_bounds__(1024) void scan_kernel(const int* __restrict__ deg,
                                                    int* __restrict__ rowstart,
                                                    int* __restrict__ cursor, int n) {
  __shared__ int sums[1024];
  int tid = threadIdx.x;
  int chunk = (n + 1023) / 1024;
  int start = tid * chunk;
  if (start > n) start = n;
  int end = start + chunk;
  if (end > n) end = n;
  int s = 0;
  for (int i = start; i < end; i++) s += deg[i];
  sums[tid] = s;
  __syncthreads();
  for (int off = 1; off < 1024; off <<= 1) {
    int v = (tid >= off) ? sums[tid - off] : 0;
    __syncthreads();
    sums[tid] += v;
    __syncthreads();
  }
  int base = (tid == 0) ? 0 : sums[tid - 1];
  for (int i = start; i < end; i++) {
    rowstart[i] = base;
    cursor[i] = base;
    base += deg[i];
  }
  if (tid == 0) rowstart[n] = sums[1023];
}

__global__ __launch_bounds__(256) void scatter_kernel(const int* __restrict__ ei,
                                                      int* __restrict__ cursor,
                                                      int* __restrict__ csr_src, int E, int N) {
  int e = blockIdx.x * 256 + threadIdx.x;
  int total = E + N;
  if (e >= total) return;
  int s, d;
  if (e < E) { s = ei[e]; d = ei[E + e]; }
  else       { s = e - E; d = e - E; }
  int p = atomicAdd(&cursor[d], 1);
  csr_src[p] = s;
}

// ---------------- weight convert: W[K][N] fp32 -> Wt_hi/Wt_lo [N][Kp] bf16, zero-pad k>=K ----

__global__ __launch_bounds__(256) void convw_kernel(const float* __restrict__ W,
                                                    short* __restrict__ Whi,
                                                    short* __restrict__ Wlo,
                                                    int K, int N, int Kp) {
  int idx = blockIdx.x * 256 + threadIdx.x;
  if (idx >= N * Kp) return;
  int n = idx / Kp, k = idx % Kp;
  float v = (k < K) ? W[(size_t)k * N + n] : 0.f;
  short hi, lo;
  split_bf16(v, hi, lo);
  Whi[idx] = hi;
  Wlo[idx] = lo;
}

// ---------------- split-bf16 MFMA GEMM: C[M][Nn] = A[M][K] @ Wt^T, 128x128 tile ----------------
// A fp32 (converted hi/lo in-kernel); Bhi/Blo are [Nn][Kp] bf16 (pre-transposed, k-padded).
// 3 MFMA streams (AhBh + AhBl + AlBh) give ~fp32 accuracy at bf16 matrix-core rate.

#define LDK 40   // padded LDS k-stride (bf16 elems): 80B rows -> uniform 2-way bank aliasing

__global__ __launch_bounds__(256, 2) void mfma_gemm_split(
    const float* __restrict__ A, const short* __restrict__ Bhi, const short* __restrict__ Blo,
    float* __restrict__ C, int M, int Nn, int K, int Kp) {
  __shared__ short Ah[128 * LDK], Al[128 * LDK], Bh[128 * LDK], Bl[128 * LDK];

  const int t = threadIdx.x;
  const int bm = blockIdx.x * 128;
  const int n0 = blockIdx.y * 128;

  const int srow = t >> 1;        // staging row 0..127
  const int shalf = t & 1;        // which 16-elem half of the 32-k tile
  const bool arow_ok = (bm + srow) < M;

  const int w = t >> 6, lane = t & 63;
  const int wm = (w >> 1) * 64, wn = (w & 1) * 64;  // wave's 64x64 quadrant
  const int lm = lane & 15, quad = lane >> 4;

  f32x4 acc[4][4];
#pragma unroll
  for (int i = 0; i < 4; i++)
#pragma unroll
    for (int j = 0; j < 4; j++) acc[i][j] = (f32x4)(0.f);

  for (int k0 = 0; k0 < Kp; k0 += 32) {
    __syncthreads();  // previous iter's frag reads done before overwrite

    // --- stage A: load 16 fp32, split to hi/lo bf16 ---
    {
      const int kbase = k0 + shalf * 16;
      f32x4 v0 = (f32x4)(0.f), v1 = (f32x4)(0.f), v2 = (f32x4)(0.f), v3 = (f32x4)(0.f);
      if (arow_ok && kbase < K) {   // K % 16 == 0 -> chunk fully in or out
        const f32x4* p = (const f32x4*)(A + (size_t)(bm + srow) * K + kbase);
        v0 = p[0]; v1 = p[1]; v2 = p[2]; v3 = p[3];
      }
      float f[16] = {v0[0], v0[1], v0[2], v0[3], v1[0], v1[1], v1[2], v1[3],
                     v2[0], v2[1], v2[2], v2[3], v3[0], v3[1], v3[2], v3[3]};
      short hi[16], lo[16];
#pragma unroll
      for (int j = 0; j < 16; j++) split_bf16(f[j], hi[j], lo[j]);
      const int la = srow * LDK + shalf * 16;
      *(short8*)&Ah[la] = *(short8*)&hi[0];
      *(short8*)&Ah[la + 8] = *(short8*)&hi[8];
      *(short8*)&Al[la] = *(short8*)&lo[0];
      *(short8*)&Al[la + 8] = *(short8*)&lo[8];
    }
    // --- stage B: bf16 already, [n][k] rows contiguous ---
    {
      const size_t gb = (size_t)(n0 + srow) * Kp + k0 + shalf * 16;
      const short8* ph = (const short8*)(Bhi + gb);
      const short8* pl = (const short8*)(Blo + gb);
      short8 h0 = ph[0], h1 = ph[1], l0 = pl[0], l1 = pl[1];
      const int la = srow * LDK + shalf * 16;
      *(short8*)&Bh[la] = h0;
      *(short8*)&Bh[la + 8] = h1;
      *(short8*)&Bl[la] = l0;
      *(short8*)&Bl[la + 8] = l1;
    }
    __syncthreads();

    // --- fragments + 48 MFMAs ---
    short8 afh[4], afl[4], bfh[4], bfl[4];
#pragma unroll
    for (int i = 0; i < 4; i++) {
      const int ra = (wm + i * 16 + lm) * LDK + quad * 8;
      afh[i] = *(const short8*)&Ah[ra];
      afl[i] = *(const short8*)&Al[ra];
      const int rb = (wn + i * 16 + lm) * LDK + quad * 8;
      bfh[i] = *(const short8*)&Bh[rb];
      bfl[i] = *(const short8*)&Bl[rb];
    }
#pragma unroll
    for (int i = 0; i < 4; i++)
#pragma unroll
      for (int j = 0; j < 4; j++) {
        acc[i][j] = __builtin_amdgcn_mfma_f32_16x16x32_bf16(afh[i], bfh[j], acc[i][j], 0, 0, 0);
        acc[i][j] = __builtin_amdgcn_mfma_f32_16x16x32_bf16(afh[i], bfl[j], acc[i][j], 0, 0, 0);
        acc[i][j] = __builtin_amdgcn_mfma_f32_16x16x32_bf16(afl[i], bfh[j], acc[i][j], 0, 0, 0);
      }
  }

  // --- epilogue: C/D layout col=lane&15, row=quad*4+reg (m89-verified) ---
#pragma unroll
  for (int i = 0; i < 4; i++) {
    const int rbase = bm + wm + i * 16 + quad * 4;
#pragma unroll
    for (int j = 0; j < 4; j++) {
      const int c = n0 + wn + j * 16 + lm;
#pragma unroll
      for (int r = 0; r < 4; r++) {
        const int row = rbase + r;
        if (row < M) C[(size_t)row * Nn + c] = acc[i][j][r];
      }
    }
  }
}

// ---------------- alpha dot products: as[n]=h[n]·a_src, ad[n]=h[n]·a_dst ----------------

__global__ __launch_bounds__(256) void alpha_kernel(const float* __restrict__ h,
                                                    const float* __restrict__ a_s,
                                                    const float* __restrict__ a_d,
                                                    float* __restrict__ as_,
                                                    float* __restrict__ ad_,
                                                    int N, int F) {
  int wid = (blockIdx.x * 256 + threadIdx.x) >> 6;
  int lane = threadIdx.x & 63;
  if (wid >= N) return;
  float ss = 0.f, dd = 0.f;
  for (int c = lane; c < F; c += 64) {
    float v = h[(int64_t)wid * F + c];
    ss += v * a_s[c];
    dd += v * a_d[c];
  }
#pragma unroll
  for (int off = 32; off; off >>= 1) {
    ss += __shfl_down(ss, off);
    dd += __shfl_down(dd, off);
  }
  if (lane == 0) { as_[wid] = ss; ad_[wid] = dd; }
}

// ---------------- per-node edge softmax + aggregate + bias (+relu) ----------------

template <int VPL>
__global__ __launch_bounds__(256) void agg_kernel(const float* __restrict__ h,
                                                  const float* __restrict__ as_,
                                                  const float* __restrict__ ad_,
                                                  const int* __restrict__ rowstart,
                                                  const int* __restrict__ csr_src,
                                                  const float* __restrict__ bias,
                                                  float* __restrict__ out,
                                                  int N, int F, int do_relu) {
  int wid = (blockIdx.x * 256 + threadIdx.x) >> 6;
  int lane = threadIdx.x & 63;
  if (wid >= N) return;
  int r0 = rowstart[wid], r1 = rowstart[wid + 1];
  float adn = ad_[wid];

  float m = -1e30f;
  for (int i = r0 + lane; i < r1; i += 64) {
    float e = as_[csr_src[i]] + adn;
    e = e > 0.f ? e : NEG_SLOPE * e;
    m = fmaxf(m, e);
  }
#pragma unroll
  for (int off = 32; off; off >>= 1) m = fmaxf(m, __shfl_xor(m, off));

  float ssum = 0.f;
  for (int i = r0 + lane; i < r1; i += 64) {
    float e = as_[csr_src[i]] + adn;
    e = e > 0.f ? e : NEG_SLOPE * e;
    ssum += __expf(e - m);
  }
#pragma unroll
  for (int off = 32; off; off >>= 1) ssum += __shfl_xor(ssum, off);
  float inv = 1.f / ssum;

  float acc[VPL];
#pragma unroll
  for (int v = 0; v < VPL; v++) acc[v] = 0.f;
  for (int k = r0; k < r1; k++) {
    int s = csr_src[k];  // wave-uniform -> broadcast load
    float e = as_[s] + adn;
    e = e > 0.f ? e : NEG_SLOPE * e;
    float w = __expf(e - m);
    const float* hrow = h + (int64_t)s * F;
#pragma unroll
    for (int v = 0; v < VPL; v++) acc[v] += w * hrow[lane + v * 64];
  }
#pragma unroll
  for (int v = 0; v < VPL; v++) {
    int c = lane + v * 64;
    float o = acc[v] * inv + bias[c];
    if (do_relu) o = fmaxf(o, 0.f);
    out[(int64_t)wid * F + c] = o;
  }
}

// ---------------- layer 3: GEMM (K x 2) + alpha3, wave per row ----------------

__global__ __launch_bounds__(256) void gemm3_kernel(const float* __restrict__ h,
                                                    const float* __restrict__ W3,
                                                    const float* __restrict__ a3s,
                                                    const float* __restrict__ a3d,
                                                    float* __restrict__ h3,
                                                    float* __restrict__ as_,
                                                    float* __restrict__ ad_,
                                                    int N, int K) {
  int wid = (blockIdx.x * 256 + threadIdx.x) >> 6;
  int lane = threadIdx.x & 63;
  if (wid >= N) return;
  float c0 = 0.f, c1 = 0.f;
  for (int k = lane; k < K; k += 64) {
    float v = h[(int64_t)wid * K + k];
    c0 += v * W3[k * 2 + 0];
    c1 += v * W3[k * 2 + 1];
  }
#pragma unroll
  for (int off = 32; off; off >>= 1) {
    c0 += __shfl_down(c0, off);
    c1 += __shfl_down(c1, off);
  }
  if (lane == 0) {
    h3[wid * 2 + 0] = c0;
    h3[wid * 2 + 1] = c1;
    as_[wid] = c0 * a3s[0] + c1 * a3s[1];
    ad_[wid] = c0 * a3d[0] + c1 * a3d[1];
  }
}

// ---------------- layer 3 aggregate + bias + final 2-class softmax ----------------

__global__ __launch_bounds__(256) void agg3_kernel(const float* __restrict__ h3,
                                                   const float* __restrict__ as_,
                                                   const float* __restrict__ ad_,
                                                   const int* __restrict__ rowstart,
                                                   const int* __restrict__ csr_src,
                                                   const float* __restrict__ b3,
                                                   float* __restrict__ out, int N) {
  int wid = (blockIdx.x * 256 + threadIdx.x) >> 6;
  int lane = threadIdx.x & 63;
  if (wid >= N) return;
  int r0 = rowstart[wid], r1 = rowstart[wid + 1];
  float adn = ad_[wid];

  float m = -1e30f;
  for (int i = r0 + lane; i < r1; i += 64) {
    float e = as_[csr_src[i]] + adn;
    e = e > 0.f ? e : NEG_SLOPE * e;
    m = fmaxf(m, e);
  }
#pragma unroll
  for (int off = 32; off; off >>= 1) m = fmaxf(m, __shfl_xor(m, off));

  float ssum = 0.f, a0 = 0.f, a1 = 0.f;
  for (int i = r0 + lane; i < r1; i += 64) {
    int s = csr_src[i];
    float e = as_[s] + adn;
    e = e > 0.f ? e : NEG_SLOPE * e;
    float w = __expf(e - m);
    ssum += w;
    a0 += w * h3[s * 2 + 0];
    a1 += w * h3[s * 2 + 1];
  }
#pragma unroll
  for (int off = 32; off; off >>= 1) {
    ssum += __shfl_xor(ssum, off);
    a0 += __shfl_xor(a0, off);
    a1 += __shfl_xor(a1, off);
  }
  if (lane == 0) {
    float inv = 1.f / ssum;
    float o0 = a0 * inv + b3[0];
    float o1 = a1 * inv + b3[1];
    float mm = fmaxf(o0, o1);
    float e0 = __expf(o0 - mm), e1 = __expf(o1 - mm);
    float d = e0 + e1;
    out[wid * 2 + 0] = e0 / d;
    out[wid * 2 + 1] = e1 / d;
  }
}

// ---------------- launcher ----------------

extern "C" void kernel_launch(void* const* d_in, const int* in_sizes, int n_in,
                              void* d_out, int out_size, void* d_ws, size_t ws_size,
                              hipStream_t stream) {
  const float* x   = (const float*)d_in[0];
  const int*   ei  = (const int*)d_in[1];
  const float* W1  = (const float*)d_in[3];
  const float* a1s = (const float*)d_in[4];
  const float* a1d = (const float*)d_in[5];
  const float* b1  = (const float*)d_in[6];
  const float* W2  = (const float*)d_in[7];
  const float* a2s = (const float*)d_in[8];
  const float* a2d = (const float*)d_in[9];
  const float* b2  = (const float*)d_in[10];
  const float* W3  = (const float*)d_in[11];
  const float* a3s = (const float*)d_in[12];
  const float* a3d = (const float*)d_in[13];
  const float* b3  = (const float*)d_in[14];

  int N   = in_sizes[2];
  int E   = in_sizes[1] / 2;
  int FIN = in_sizes[0] / N;    // 784
  int d1  = in_sizes[4];        // 128
  int d2  = in_sizes[8];        // 256
  int Kp1 = ((FIN + 31) / 32) * 32;  // 800

  // workspace carve
  char* p = (char*)d_ws;
  float* buf1 = (float*)p; p += (size_t)N * d2 * sizeof(float);
  float* buf2 = (float*)p; p += (size_t)N * d2 * sizeof(float);
  float* h3   = (float*)p; p += (size_t)N * 2 * sizeof(float);
  float* as_  = (float*)p; p += (size_t)N * sizeof(float);
  float* ad_  = (float*)p; p += (size_t)N * sizeof(float);
  int* deg      = (int*)p; p += (size_t)N * sizeof(int);
  int* rowstart = (int*)p; p += (size_t)(N + 1) * sizeof(int);
  int* cursor   = (int*)p; p += (size_t)N * sizeof(int);
  int* csr      = (int*)p; p += (size_t)(E + N) * sizeof(int);
  p = (char*)(((uintptr_t)p + 255) & ~(uintptr_t)255);  // 16B+ align for short8 loads
  short* w1h = (short*)p; p += (size_t)d1 * Kp1 * sizeof(short);
  short* w1l = (short*)p; p += (size_t)d1 * Kp1 * sizeof(short);
  short* w2h = (short*)p; p += (size_t)d2 * d1 * sizeof(short);
  short* w2l = (short*)p; p += (size_t)d2 * d1 * sizeof(short);

  // CSR build
  hipMemsetAsync(deg, 0, (size_t)N * sizeof(int), stream);
  int tot = E + N;
  hist_kernel<<<(tot + 255) / 256, 256, 0, stream>>>(ei, deg, E, N);
  scan_kernel<<<1, 1024, 0, stream>>>(deg, rowstart, cursor, N);
  scatter_kernel<<<(tot + 255) / 256, 256, 0, stream>>>(ei, cursor, csr, E, N);

  // weight transpose+split (tiny)
  convw_kernel<<<(d1 * Kp1 + 255) / 256, 256, 0, stream>>>(W1, w1h, w1l, FIN, d1, Kp1);
  convw_kernel<<<(d2 * d1 + 255) / 256, 256, 0, stream>>>(W2, w2h, w2l, d1, d2, d1);

  int wb = (N + 3) / 4;  // wave-per-node, 4 waves/block

  // layer 1: x@W1 -> buf1 [N,128]; agg -> buf2 (relu)
  {
    dim3 g((N + 127) / 128, d1 / 128);
    mfma_gemm_split<<<g, 256, 0, stream>>>(x, w1h, w1l, buf1, N, d1, FIN, Kp1);
    alpha_kernel<<<wb, 256, 0, stream>>>(buf1, a1s, a1d, as_, ad_, N, d1);
    agg_kernel<2><<<wb, 256, 0, stream>>>(buf1, as_, ad_, rowstart, csr, b1, buf2, N, d1, 1);
  }
  // layer 2: buf2@W2 -> buf1 [N,256]; agg -> buf2 (relu)
  {
    dim3 g((N + 127) / 128, d2 / 128);
    mfma_gemm_split<<<g, 256, 0, stream>>>(buf2, w2h, w2l, buf1, N, d2, d1, d1);
    alpha_kernel<<<wb, 256, 0, stream>>>(buf1, a2s, a2d, as_, ad_, N, d2);
    agg_kernel<4><<<wb, 256, 0, stream>>>(buf1, as_, ad_, rowstart, csr, b2, buf2, N, d2, 1);
  }
  // layer 3: buf2@W3 -> h3 [N,2]; agg + bias + softmax -> d_out
  {
    gemm3_kernel<<<wb, 256, 0, stream>>>(buf2, W3, a3s, a3d, h3, as_, ad_, N, d2);
    agg3_kernel<<<wb, 256, 0, stream>>>(h3, as_, ad_, rowstart, csr, b3, (float*)d_out, N);
  }
}

// Round 3
// 1459.764 us; speedup vs baseline: 1.3580x; 1.0402x over previous
//
#include <hip/hip_runtime.h>
#include <cstdint>

#define NEG_SLOPE 0.2f

typedef __attribute__((ext_vector_type(8))) short short8;     // 8 bf16 = 4 VGPRs
typedef __attribute__((ext_vector_type(4))) float f32x4;
typedef __attribute__((ext_vector_type(2))) float f32x2;
typedef __attribute__((ext_vector_type(4))) unsigned short ushort4v;
typedef __attribute__((ext_vector_type(2))) unsigned short ushort2v;

// split fp32 v into bf16 hi + bf16 lo (truncation; hi+lo ~ v to ~2^-16 rel)
__device__ inline void split_bf16(float v, short& hi, short& lo) {
  unsigned u = __builtin_bit_cast(unsigned, v);
  hi = (short)(u >> 16);
  float hif = __builtin_bit_cast(float, u & 0xffff0000u);
  float r = v - hif;
  lo = (short)(__builtin_bit_cast(unsigned, r) >> 16);
}

__device__ inline float b2f(unsigned short u) {
  return __builtin_bit_cast(float, (unsigned)u << 16);
}
__device__ inline unsigned short f2b_rne(float f) {
  unsigned u = __builtin_bit_cast(unsigned, f);
  return (unsigned short)((u + 0x7fffu + ((u >> 16) & 1u)) >> 16);
}

// ---------------- CSR build ----------------

__global__ __launch_bounds__(256) void hist_kernel(const int* __restrict__ ei,
                                                   int* __restrict__ deg, int E, int N) {
  int e = blockIdx.x * 256 + threadIdx.x;
  int total = E + N;
  if (e >= total) return;
  int d = (e < E) ? ei[E + e] : (e - E);   // self-loop for virtual edges
  atomicAdd(&deg[d], 1);
}

__global__ __launch_bounds__(1024) void scan_kernel(const int* __restrict__ deg,
                                                    int* __restrict__ rowstart,
                                                    int* __restrict__ cursor, int n) {
  __shared__ int sums[1024];
  int tid = threadIdx.x;
  int chunk = (n + 1023) / 1024;
  int start = tid * chunk;
  if (start > n) start = n;
  int end = start + chunk;
  if (end > n) end = n;
  int s = 0;
  for (int i = start; i < end; i++) s += deg[i];
  sums[tid] = s;
  __syncthreads();
  for (int off = 1; off < 1024; off <<= 1) {
    int v = (tid >= off) ? sums[tid - off] : 0;
    __syncthreads();
    sums[tid] += v;
    __syncthreads();
  }
  int base = (tid == 0) ? 0 : sums[tid - 1];
  for (int i = start; i < end; i++) {
    rowstart[i] = base;
    cursor[i] = base;
    base += deg[i];
  }
  if (tid == 0) rowstart[n] = sums[1023];
}

__global__ __launch_bounds__(256) void scatter_kernel(const int* __restrict__ ei,
                                                      int* __restrict__ cursor,
                                                      int* __restrict__ csr_src, int E, int N) {
  int e = blockIdx.x * 256 + threadIdx.x;
  int total = E + N;
  if (e >= total) return;
  int s, d;
  if (e < E) { s = ei[e]; d = ei[E + e]; }
  else       { s = e - E; d = e - E; }
  int p = atomicAdd(&cursor[d], 1);
  csr_src[p] = s;
}

// ---------------- weight convert: W[K][N] fp32 -> Wt_hi/Wt_lo [N][Kp] bf16, zero-pad ----

__global__ __launch_bounds__(256) void convw_kernel(const float* __restrict__ W,
                                                    short* __restrict__ Whi,
                                                    short* __restrict__ Wlo,
                                                    int K, int N, int Kp) {
  int idx = blockIdx.x * 256 + threadIdx.x;
  if (idx >= N * Kp) return;
  int n = idx / Kp, k = idx % Kp;
  float v = (k < K) ? W[(size_t)k * N + n] : 0.f;
  short hi, lo;
  split_bf16(v, hi, lo);
  Whi[idx] = hi;
  Wlo[idx] = lo;
}

// ---------------- split-bf16 MFMA GEMM: C[M][Nn](bf16) = A[M][K](f32) @ Wt^T ----------------

#define LDK 40   // padded LDS k-stride (bf16 elems): 80B rows -> uniform 2-way bank aliasing

__global__ __launch_bounds__(256, 2) void mfma_gemm_split(
    const float* __restrict__ A, const short* __restrict__ Bhi, const short* __restrict__ Blo,
    unsigned short* __restrict__ C, int M, int Nn, int K, int Kp) {
  __shared__ short Ah[128 * LDK], Al[128 * LDK], Bh[128 * LDK], Bl[128 * LDK];

  const int t = threadIdx.x;
  const int bm = blockIdx.x * 128;
  const int n0 = blockIdx.y * 128;

  const int srow = t >> 1;        // staging row 0..127
  const int shalf = t & 1;        // which 16-elem half of the 32-k tile
  const bool arow_ok = (bm + srow) < M;

  const int w = t >> 6, lane = t & 63;
  const int wm = (w >> 1) * 64, wn = (w & 1) * 64;  // wave's 64x64 quadrant
  const int lm = lane & 15, quad = lane >> 4;

  f32x4 acc[4][4];
#pragma unroll
  for (int i = 0; i < 4; i++)
#pragma unroll
    for (int j = 0; j < 4; j++) acc[i][j] = (f32x4)(0.f);

  for (int k0 = 0; k0 < Kp; k0 += 32) {
    __syncthreads();

    // --- stage A: load 16 fp32, split to hi/lo bf16 ---
    {
      const int kbase = k0 + shalf * 16;
      f32x4 v0 = (f32x4)(0.f), v1 = (f32x4)(0.f), v2 = (f32x4)(0.f), v3 = (f32x4)(0.f);
      if (arow_ok && kbase < K) {   // K % 16 == 0 -> chunk fully in or out
        const f32x4* p = (const f32x4*)(A + (size_t)(bm + srow) * K + kbase);
        v0 = p[0]; v1 = p[1]; v2 = p[2]; v3 = p[3];
      }
      float f[16] = {v0[0], v0[1], v0[2], v0[3], v1[0], v1[1], v1[2], v1[3],
                     v2[0], v2[1], v2[2], v2[3], v3[0], v3[1], v3[2], v3[3]};
      short hi[16], lo[16];
#pragma unroll
      for (int j = 0; j < 16; j++) split_bf16(f[j], hi[j], lo[j]);
      const int la = srow * LDK + shalf * 16;
      *(short8*)&Ah[la] = *(short8*)&hi[0];
      *(short8*)&Ah[la + 8] = *(short8*)&hi[8];
      *(short8*)&Al[la] = *(short8*)&lo[0];
      *(short8*)&Al[la + 8] = *(short8*)&lo[8];
    }
    // --- stage B ---
    {
      const size_t gb = (size_t)(n0 + srow) * Kp + k0 + shalf * 16;
      const short8* ph = (const short8*)(Bhi + gb);
      const short8* pl = (const short8*)(Blo + gb);
      short8 h0 = ph[0], h1 = ph[1], l0 = pl[0], l1 = pl[1];
      const int la = srow * LDK + shalf * 16;
      *(short8*)&Bh[la] = h0;
      *(short8*)&Bh[la + 8] = h1;
      *(short8*)&Bl[la] = l0;
      *(short8*)&Bl[la + 8] = l1;
    }
    __syncthreads();

    // --- fragments + 48 MFMAs ---
    short8 afh[4], afl[4], bfh[4], bfl[4];
#pragma unroll
    for (int i = 0; i < 4; i++) {
      const int ra = (wm + i * 16 + lm) * LDK + quad * 8;
      afh[i] = *(const short8*)&Ah[ra];
      afl[i] = *(const short8*)&Al[ra];
      const int rb = (wn + i * 16 + lm) * LDK + quad * 8;
      bfh[i] = *(const short8*)&Bh[rb];
      bfl[i] = *(const short8*)&Bl[rb];
    }
#pragma unroll
    for (int i = 0; i < 4; i++)
#pragma unroll
      for (int j = 0; j < 4; j++) {
        acc[i][j] = __builtin_amdgcn_mfma_f32_16x16x32_bf16(afh[i], bfh[j], acc[i][j], 0, 0, 0);
        acc[i][j] = __builtin_amdgcn_mfma_f32_16x16x32_bf16(afh[i], bfl[j], acc[i][j], 0, 0, 0);
        acc[i][j] = __builtin_amdgcn_mfma_f32_16x16x32_bf16(afl[i], bfh[j], acc[i][j], 0, 0, 0);
      }
  }

  // --- epilogue: C/D layout col=lane&15, row=quad*4+reg; write bf16 (RNE) ---
#pragma unroll
  for (int i = 0; i < 4; i++) {
    const int rbase = bm + wm + i * 16 + quad * 4;
#pragma unroll
    for (int j = 0; j < 4; j++) {
      const int c = n0 + wn + j * 16 + lm;
#pragma unroll
      for (int r = 0; r < 4; r++) {
        const int row = rbase + r;
        if (row < M) C[(size_t)row * Nn + c] = f2b_rne(acc[i][j][r]);
      }
    }
  }
}

// ---------------- alpha dot products from bf16 h ----------------

__global__ __launch_bounds__(256) void alpha_kernel(const unsigned short* __restrict__ h,
                                                    const float* __restrict__ a_s,
                                                    const float* __restrict__ a_d,
                                                    float* __restrict__ as_,
                                                    float* __restrict__ ad_,
                                                    int N, int F) {
  int wid = (blockIdx.x * 256 + threadIdx.x) >> 6;
  int lane = threadIdx.x & 63;
  if (wid >= N) return;
  float ss = 0.f, dd = 0.f;
  for (int c = lane; c < F; c += 64) {
    float v = b2f(h[(int64_t)wid * F + c]);
    ss += v * a_s[c];
    dd += v * a_d[c];
  }
#pragma unroll
  for (int off = 32; off; off >>= 1) {
    ss += __shfl_down(ss, off);
    dd += __shfl_down(dd, off);
  }
  if (lane == 0) { as_[wid] = ss; ad_[wid] = dd; }
}

// ---------------- per-node edge softmax + aggregate + bias (+relu), bf16 gather ----------------
// lane owns VPL CONTIGUOUS columns [lane*VPL, lane*VPL+VPL) -> ushort2/4 vector gathers

template <int VPL>
__global__ __launch_bounds__(256) void agg_kernel(const unsigned short* __restrict__ h,
                                                  const float* __restrict__ as_,
                                                  const float* __restrict__ ad_,
                                                  const int* __restrict__ rowstart,
                                                  const int* __restrict__ csr_src,
                                                  const float* __restrict__ bias,
                                                  float* __restrict__ out,
                                                  int N, int F, int do_relu) {
  int wid = (blockIdx.x * 256 + threadIdx.x) >> 6;
  int lane = threadIdx.x & 63;
  if (wid >= N) return;
  int r0 = rowstart[wid], r1 = rowstart[wid + 1];
  float adn = ad_[wid];

  // pass 1: segment max
  float m = -1e30f;
  for (int i = r0 + lane; i < r1; i += 64) {
    float e = as_[csr_src[i]] + adn;
    e = e > 0.f ? e : NEG_SLOPE * e;
    m = fmaxf(m, e);
  }
#pragma unroll
  for (int off = 32; off; off >>= 1) m = fmaxf(m, __shfl_xor(m, off));

  // pass 2: segment sum of exp
  float ssum = 0.f;
  for (int i = r0 + lane; i < r1; i += 64) {
    float e = as_[csr_src[i]] + adn;
    e = e > 0.f ? e : NEG_SLOPE * e;
    ssum += __expf(e - m);
  }
#pragma unroll
  for (int off = 32; off; off >>= 1) ssum += __shfl_xor(ssum, off);
  float inv = 1.f / ssum;

  // pass 3: weighted aggregate; lane owns VPL contiguous cols
  const int cbase = lane * VPL;
  float acc[VPL];
#pragma unroll
  for (int v = 0; v < VPL; v++) acc[v] = 0.f;
  for (int k = r0; k < r1; k++) {
    int s = csr_src[k];  // wave-uniform -> broadcast load
    float e = as_[s] + adn;
    e = e > 0.f ? e : NEG_SLOPE * e;
    float w = __expf(e - m);
    const unsigned short* hrow = h + (int64_t)s * F + cbase;
    unsigned short uv[VPL];
    if (VPL == 4) *(ushort4v*)uv = *(const ushort4v*)hrow;
    else          *(ushort2v*)uv = *(const ushort2v*)hrow;
#pragma unroll
    for (int v = 0; v < VPL; v++) acc[v] += w * b2f(uv[v]);
  }
  float ov[VPL];
#pragma unroll
  for (int v = 0; v < VPL; v++) {
    float o = acc[v] * inv + bias[cbase + v];
    if (do_relu) o = fmaxf(o, 0.f);
    ov[v] = o;
  }
  float* op = out + (int64_t)wid * F + cbase;
  if (VPL == 4) *(f32x4*)op = *(f32x4*)ov;
  else          *(f32x2*)op = *(f32x2*)ov;
}

// ---------------- layer 3: GEMM (K x 2) + alpha3, wave per row ----------------

__global__ __launch_bounds__(256) void gemm3_kernel(const float* __restrict__ h,
                                                    const float* __restrict__ W3,
                                                    const float* __restrict__ a3s,
                                                    const float* __restrict__ a3d,
                                                    float* __restrict__ h3,
                                                    float* __restrict__ as_,
                                                    float* __restrict__ ad_,
                                                    int N, int K) {
  int wid = (blockIdx.x * 256 + threadIdx.x) >> 6;
  int lane = threadIdx.x & 63;
  if (wid >= N) return;
  float c0 = 0.f, c1 = 0.f;
  for (int k = lane; k < K; k += 64) {
    float v = h[(int64_t)wid * K + k];
    c0 += v * W3[k * 2 + 0];
    c1 += v * W3[k * 2 + 1];
  }
#pragma unroll
  for (int off = 32; off; off >>= 1) {
    c0 += __shfl_down(c0, off);
    c1 += __shfl_down(c1, off);
  }
  if (lane == 0) {
    h3[wid * 2 + 0] = c0;
    h3[wid * 2 + 1] = c1;
    as_[wid] = c0 * a3s[0] + c1 * a3s[1];
    ad_[wid] = c0 * a3d[0] + c1 * a3d[1];
  }
}

// ---------------- layer 3 aggregate + bias + final 2-class softmax ----------------

__global__ __launch_bounds__(256) void agg3_kernel(const float* __restrict__ h3,
                                                   const float* __restrict__ as_,
                                                   const float* __restrict__ ad_,
                                                   const int* __restrict__ rowstart,
                                                   const int* __restrict__ csr_src,
                                                   const float* __restrict__ b3,
                                                   float* __restrict__ out, int N) {
  int wid = (blockIdx.x * 256 + threadIdx.x) >> 6;
  int lane = threadIdx.x & 63;
  if (wid >= N) return;
  int r0 = rowstart[wid], r1 = rowstart[wid + 1];
  float adn = ad_[wid];

  float m = -1e30f;
  for (int i = r0 + lane; i < r1; i += 64) {
    float e = as_[csr_src[i]] + adn;
    e = e > 0.f ? e : NEG_SLOPE * e;
    m = fmaxf(m, e);
  }
#pragma unroll
  for (int off = 32; off; off >>= 1) m = fmaxf(m, __shfl_xor(m, off));

  float ssum = 0.f, a0 = 0.f, a1 = 0.f;
  for (int i = r0 + lane; i < r1; i += 64) {
    int s = csr_src[i];
    float e = as_[s] + adn;
    e = e > 0.f ? e : NEG_SLOPE * e;
    float w = __expf(e - m);
    ssum += w;
    a0 += w * h3[s * 2 + 0];
    a1 += w * h3[s * 2 + 1];
  }
#pragma unroll
  for (int off = 32; off; off >>= 1) {
    ssum += __shfl_xor(ssum, off);
    a0 += __shfl_xor(a0, off);
    a1 += __shfl_xor(a1, off);
  }
  if (lane == 0) {
    float inv = 1.f / ssum;
    float o0 = a0 * inv + b3[0];
    float o1 = a1 * inv + b3[1];
    float mm = fmaxf(o0, o1);
    float e0 = __expf(o0 - mm), e1 = __expf(o1 - mm);
    float d = e0 + e1;
    out[wid * 2 + 0] = e0 / d;
    out[wid * 2 + 1] = e1 / d;
  }
}

// ---------------- launcher ----------------

extern "C" void kernel_launch(void* const* d_in, const int* in_sizes, int n_in,
                              void* d_out, int out_size, void* d_ws, size_t ws_size,
                              hipStream_t stream) {
  const float* x   = (const float*)d_in[0];
  const int*   ei  = (const int*)d_in[1];
  const float* W1  = (const float*)d_in[3];
  const float* a1s = (const float*)d_in[4];
  const float* a1d = (const float*)d_in[5];
  const float* b1  = (const float*)d_in[6];
  const float* W2  = (const float*)d_in[7];
  const float* a2s = (const float*)d_in[8];
  const float* a2d = (const float*)d_in[9];
  const float* b2  = (const float*)d_in[10];
  const float* W3  = (const float*)d_in[11];
  const float* a3s = (const float*)d_in[12];
  const float* a3d = (const float*)d_in[13];
  const float* b3  = (const float*)d_in[14];

  int N   = in_sizes[2];
  int E   = in_sizes[1] / 2;
  int FIN = in_sizes[0] / N;    // 784
  int d1  = in_sizes[4];        // 128
  int d2  = in_sizes[8];        // 256
  int Kp1 = ((FIN + 31) / 32) * 32;  // 800

  // workspace carve
  char* p = (char*)d_ws;
  unsigned short* hbuf = (unsigned short*)p; p += (size_t)N * d2 * sizeof(float);  // bf16 h (over-sized, keeps alignment)
  float* buf2 = (float*)p; p += (size_t)N * d2 * sizeof(float);
  float* h3   = (float*)p; p += (size_t)N * 2 * sizeof(float);
  float* as_  = (float*)p; p += (size_t)N * sizeof(float);
  float* ad_  = (float*)p; p += (size_t)N * sizeof(float);
  int* deg      = (int*)p; p += (size_t)N * sizeof(int);
  int* rowstart = (int*)p; p += (size_t)(N + 1) * sizeof(int);
  int* cursor   = (int*)p; p += (size_t)N * sizeof(int);
  int* csr      = (int*)p; p += (size_t)(E + N) * sizeof(int);
  p = (char*)(((uintptr_t)p + 255) & ~(uintptr_t)255);
  short* w1h = (short*)p; p += (size_t)d1 * Kp1 * sizeof(short);
  short* w1l = (short*)p; p += (size_t)d1 * Kp1 * sizeof(short);
  short* w2h = (short*)p; p += (size_t)d2 * d1 * sizeof(short);
  short* w2l = (short*)p; p += (size_t)d2 * d1 * sizeof(short);

  // CSR build
  hipMemsetAsync(deg, 0, (size_t)N * sizeof(int), stream);
  int tot = E + N;
  hist_kernel<<<(tot + 255) / 256, 256, 0, stream>>>(ei, deg, E, N);
  scan_kernel<<<1, 1024, 0, stream>>>(deg, rowstart, cursor, N);
  scatter_kernel<<<(tot + 255) / 256, 256, 0, stream>>>(ei, cursor, csr, E, N);

  // weight transpose+split (tiny)
  convw_kernel<<<(d1 * Kp1 + 255) / 256, 256, 0, stream>>>(W1, w1h, w1l, FIN, d1, Kp1);
  convw_kernel<<<(d2 * d1 + 255) / 256, 256, 0, stream>>>(W2, w2h, w2l, d1, d2, d1);

  int wb = (N + 3) / 4;  // wave-per-node, 4 waves/block

  // layer 1: x@W1 -> hbuf bf16 [N,128]; agg -> buf2 fp32 (relu)
  {
    dim3 g((N + 127) / 128, d1 / 128);
    mfma_gemm_split<<<g, 256, 0, stream>>>(x, w1h, w1l, hbuf, N, d1, FIN, Kp1);
    alpha_kernel<<<wb, 256, 0, stream>>>(hbuf, a1s, a1d, as_, ad_, N, d1);
    agg_kernel<2><<<wb, 256, 0, stream>>>(hbuf, as_, ad_, rowstart, csr, b1, buf2, N, d1, 1);
  }
  // layer 2: buf2@W2 -> hbuf bf16 [N,256]; agg -> buf2 fp32 (relu)
  {
    dim3 g((N + 127) / 128, d2 / 128);
    mfma_gemm_split<<<g, 256, 0, stream>>>(buf2, w2h, w2l, hbuf, N, d2, d1, d1);
    alpha_kernel<<<wb, 256, 0, stream>>>(hbuf, a2s, a2d, as_, ad_, N, d2);
    agg_kernel<4><<<wb, 256, 0, stream>>>(hbuf, as_, ad_, rowstart, csr, b2, buf2, N, d2, 1);
  }
  // layer 3: buf2@W3 -> h3 [N,2]; agg + bias + softmax -> d_out
  {
    gemm3_kernel<<<wb, 256, 0, stream>>>(buf2, W3, a3s, a3d, h3, as_, ad_, N, d2);
    agg3_kernel<<<wb, 256, 0, stream>>>(h3, as_, ad_, rowstart, csr, b3, (float*)d_out, N);
  }
}

// Round 4
// 1258.624 us; speedup vs baseline: 1.5750x; 1.1598x over previous
//
#include <hip/hip_runtime.h>
#include <cstdint>

#define NEG_SLOPE 0.2f

typedef __attribute__((ext_vector_type(8))) short short8;     // 8 bf16 = 4 VGPRs
typedef __attribute__((ext_vector_type(4))) float f32x4;
typedef __attribute__((ext_vector_type(2))) float f32x2;
typedef __attribute__((ext_vector_type(4))) unsigned short ushort4v;
typedef __attribute__((ext_vector_type(2))) unsigned short ushort2v;

// split fp32 v into bf16 hi + bf16 lo (truncation; hi+lo ~ v to ~2^-16 rel)
__device__ inline void split_bf16(float v, short& hi, short& lo) {
  unsigned u = __builtin_bit_cast(unsigned, v);
  hi = (short)(u >> 16);
  float hif = __builtin_bit_cast(float, u & 0xffff0000u);
  float r = v - hif;
  lo = (short)(__builtin_bit_cast(unsigned, r) >> 16);
}

__device__ inline float b2f(unsigned short u) {
  return __builtin_bit_cast(float, (unsigned)u << 16);
}
__device__ inline unsigned short f2b_rne(float f) {
  unsigned u = __builtin_bit_cast(unsigned, f);
  return (unsigned short)((u + 0x7fffu + ((u >> 16) & 1u)) >> 16);
}

// ---------------- CSR build ----------------

__global__ __launch_bounds__(256) void hist_kernel(const int* __restrict__ ei,
                                                   int* __restrict__ deg, int E, int N) {
  int e = blockIdx.x * 256 + threadIdx.x;
  int total = E + N;
  if (e >= total) return;
  int d = (e < E) ? ei[E + e] : (e - E);   // self-loop for virtual edges
  atomicAdd(&deg[d], 1);
}

// ---- 3-phase device-wide exclusive scan of deg[0..n) (chunk=1024/block; n<=262144) ----

__global__ __launch_bounds__(256) void scan_phaseA(const int* __restrict__ deg,
                                                   int* __restrict__ bsum, int n) {
  __shared__ int red[256];
  int base = blockIdx.x * 1024;
  int s = 0;
#pragma unroll
  for (int j = 0; j < 4; j++) {
    int i = base + threadIdx.x + j * 256;
    if (i < n) s += deg[i];
  }
  red[threadIdx.x] = s;
  __syncthreads();
  for (int off = 128; off; off >>= 1) {
    if (threadIdx.x < off) red[threadIdx.x] += red[threadIdx.x + off];
    __syncthreads();
  }
  if (threadIdx.x == 0) bsum[blockIdx.x] = red[0];
}

__global__ __launch_bounds__(256) void scan_phaseB(int* __restrict__ bsum,
                                                   int* __restrict__ rowstart,
                                                   int nb, int n) {
  __shared__ int sc[256];
  int tid = threadIdx.x;
  int v = (tid < nb) ? bsum[tid] : 0;
  sc[tid] = v;
  __syncthreads();
  for (int off = 1; off < 256; off <<= 1) {
    int t = (tid >= off) ? sc[tid - off] : 0;
    __syncthreads();
    sc[tid] += t;
    __syncthreads();
  }
  if (tid < nb) bsum[tid] = sc[tid] - v;   // exclusive block offsets
  if (tid == 0) rowstart[n] = sc[255];     // grand total
}

__global__ __launch_bounds__(256) void scan_phaseC(const int* __restrict__ deg,
                                                   const int* __restrict__ bsum,
                                                   int* __restrict__ rowstart,
                                                   int* __restrict__ cursor, int n) {
  __shared__ int tsum[256];
  int tid = threadIdx.x;
  int base = blockIdx.x * 1024 + tid * 4;  // 4 contiguous per thread
  int d[4];
  int s = 0;
#pragma unroll
  for (int j = 0; j < 4; j++) {
    int i = base + j;
    d[j] = (i < n) ? deg[i] : 0;
    s += d[j];
  }
  tsum[tid] = s;
  __syncthreads();
  for (int off = 1; off < 256; off <<= 1) {
    int t = (tid >= off) ? tsum[tid - off] : 0;
    __syncthreads();
    tsum[tid] += t;
    __syncthreads();
  }
  int run = bsum[blockIdx.x] + tsum[tid] - s;  // exclusive prefix for this thread
#pragma unroll
  for (int j = 0; j < 4; j++) {
    int i = base + j;
    if (i < n) { rowstart[i] = run; cursor[i] = run; }
    run += d[j];
  }
}

__global__ __launch_bounds__(256) void scatter_kernel(const int* __restrict__ ei,
                                                      int* __restrict__ cursor,
                                                      int* __restrict__ csr_src, int E, int N) {
  int e = blockIdx.x * 256 + threadIdx.x;
  int total = E + N;
  if (e >= total) return;
  int s, d;
  if (e < E) { s = ei[e]; d = ei[E + e]; }
  else       { s = e - E; d = e - E; }
  int p = atomicAdd(&cursor[d], 1);
  csr_src[p] = s;
}

// ---------------- weight convert: W[K][N] fp32 -> Wt_hi/Wt_lo [N][Kp] bf16, zero-pad ----

__global__ __launch_bounds__(256) void convw_kernel(const float* __restrict__ W,
                                                    short* __restrict__ Whi,
                                                    short* __restrict__ Wlo,
                                                    int K, int N, int Kp) {
  int idx = blockIdx.x * 256 + threadIdx.x;
  if (idx >= N * Kp) return;
  int n = idx / Kp, k = idx % Kp;
  float v = (k < K) ? W[(size_t)k * N + n] : 0.f;
  short hi, lo;
  split_bf16(v, hi, lo);
  Whi[idx] = hi;
  Wlo[idx] = lo;
}

// ---------------- split-bf16 MFMA GEMM: C[M][Nn](bf16) = A[M][K](f32) @ Wt^T ----------------

#define LDK 40   // padded LDS k-stride: 80B rows -> uniform 2-way bank aliasing (free, m136)

__global__ __launch_bounds__(256, 2) void mfma_gemm_split(
    const float* __restrict__ A, const short* __restrict__ Bhi, const short* __restrict__ Blo,
    unsigned short* __restrict__ C, int M, int Nn, int K, int Kp) {
  __shared__ short Ah[128 * LDK], Al[128 * LDK], Bh[128 * LDK], Bl[128 * LDK];

  const int t = threadIdx.x;
  const int bm = blockIdx.x * 128;
  const int n0 = blockIdx.y * 128;

  const int srow = t >> 1;        // staging row 0..127
  const int shalf = t & 1;        // which 16-elem half of the 32-k tile
  const bool arow_ok = (bm + srow) < M;

  const int w = t >> 6, lane = t & 63;
  const int wm = (w >> 1) * 64, wn = (w & 1) * 64;  // wave's 64x64 quadrant
  const int lm = lane & 15, quad = lane >> 4;

  f32x4 acc[4][4];
#pragma unroll
  for (int i = 0; i < 4; i++)
#pragma unroll
    for (int j = 0; j < 4; j++) acc[i][j] = (f32x4)(0.f);

  for (int k0 = 0; k0 < Kp; k0 += 32) {
    __syncthreads();

    // --- stage A: load 16 fp32, split to hi/lo bf16 ---
    {
      const int kbase = k0 + shalf * 16;
      f32x4 v0 = (f32x4)(0.f), v1 = (f32x4)(0.f), v2 = (f32x4)(0.f), v3 = (f32x4)(0.f);
      if (arow_ok && kbase < K) {   // K % 16 == 0 -> chunk fully in or out
        const f32x4* p = (const f32x4*)(A + (size_t)(bm + srow) * K + kbase);
        v0 = p[0]; v1 = p[1]; v2 = p[2]; v3 = p[3];
      }
      float f[16] = {v0[0], v0[1], v0[2], v0[3], v1[0], v1[1], v1[2], v1[3],
                     v2[0], v2[1], v2[2], v2[3], v3[0], v3[1], v3[2], v3[3]};
      short hi[16], lo[16];
#pragma unroll
      for (int j = 0; j < 16; j++) split_bf16(f[j], hi[j], lo[j]);
      const int la = srow * LDK + shalf * 16;
      *(short8*)&Ah[la] = *(short8*)&hi[0];
      *(short8*)&Ah[la + 8] = *(short8*)&hi[8];
      *(short8*)&Al[la] = *(short8*)&lo[0];
      *(short8*)&Al[la + 8] = *(short8*)&lo[8];
    }
    // --- stage B ---
    {
      const size_t gb = (size_t)(n0 + srow) * Kp + k0 + shalf * 16;
      const short8* ph = (const short8*)(Bhi + gb);
      const short8* pl = (const short8*)(Blo + gb);
      short8 h0 = ph[0], h1 = ph[1], l0 = pl[0], l1 = pl[1];
      const int la = srow * LDK + shalf * 16;
      *(short8*)&Bh[la] = h0;
      *(short8*)&Bh[la + 8] = h1;
      *(short8*)&Bl[la] = l0;
      *(short8*)&Bl[la + 8] = l1;
    }
    __syncthreads();

    // --- fragments + 48 MFMAs ---
    short8 afh[4], afl[4], bfh[4], bfl[4];
#pragma unroll
    for (int i = 0; i < 4; i++) {
      const int ra = (wm + i * 16 + lm) * LDK + quad * 8;
      afh[i] = *(const short8*)&Ah[ra];
      afl[i] = *(const short8*)&Al[ra];
      const int rb = (wn + i * 16 + lm) * LDK + quad * 8;
      bfh[i] = *(const short8*)&Bh[rb];
      bfl[i] = *(const short8*)&Bl[rb];
    }
#pragma unroll
    for (int i = 0; i < 4; i++)
#pragma unroll
      for (int j = 0; j < 4; j++) {
        acc[i][j] = __builtin_amdgcn_mfma_f32_16x16x32_bf16(afh[i], bfh[j], acc[i][j], 0, 0, 0);
        acc[i][j] = __builtin_amdgcn_mfma_f32_16x16x32_bf16(afh[i], bfl[j], acc[i][j], 0, 0, 0);
        acc[i][j] = __builtin_amdgcn_mfma_f32_16x16x32_bf16(afl[i], bfh[j], acc[i][j], 0, 0, 0);
      }
  }

  // --- epilogue: C/D layout col=lane&15, row=quad*4+reg; write bf16 (RNE) ---
#pragma unroll
  for (int i = 0; i < 4; i++) {
    const int rbase = bm + wm + i * 16 + quad * 4;
#pragma unroll
    for (int j = 0; j < 4; j++) {
      const int c = n0 + wn + j * 16 + lm;
#pragma unroll
      for (int r = 0; r < 4; r++) {
        const int row = rbase + r;
        if (row < M) C[(size_t)row * Nn + c] = f2b_rne(acc[i][j][r]);
      }
    }
  }
}

// ---------------- alpha dot products from bf16 h ----------------

__global__ __launch_bounds__(256) void alpha_kernel(const unsigned short* __restrict__ h,
                                                    const float* __restrict__ a_s,
                                                    const float* __restrict__ a_d,
                                                    float* __restrict__ as_,
                                                    float* __restrict__ ad_,
                                                    int N, int F) {
  int wid = (blockIdx.x * 256 + threadIdx.x) >> 6;
  int lane = threadIdx.x & 63;
  if (wid >= N) return;
  float ss = 0.f, dd = 0.f;
  for (int c = lane; c < F; c += 64) {
    float v = b2f(h[(int64_t)wid * F + c]);
    ss += v * a_s[c];
    dd += v * a_d[c];
  }
#pragma unroll
  for (int off = 32; off; off >>= 1) {
    ss += __shfl_down(ss, off);
    dd += __shfl_down(dd, off);
  }
  if (lane == 0) { as_[wid] = ss; ad_[wid] = dd; }
}

// ---------------- per-node edge softmax + aggregate + bias (+relu), bf16 gather ----------------

template <int VPL>
__global__ __launch_bounds__(256) void agg_kernel(const unsigned short* __restrict__ h,
                                                  const float* __restrict__ as_,
                                                  const float* __restrict__ ad_,
                                                  const int* __restrict__ rowstart,
                                                  const int* __restrict__ csr_src,
                                                  const float* __restrict__ bias,
                                                  float* __restrict__ out,
                                                  int N, int F, int do_relu) {
  int wid = (blockIdx.x * 256 + threadIdx.x) >> 6;
  int lane = threadIdx.x & 63;
  if (wid >= N) return;
  int r0 = rowstart[wid], r1 = rowstart[wid + 1];
  float adn = ad_[wid];

  float m = -1e30f;
  for (int i = r0 + lane; i < r1; i += 64) {
    float e = as_[csr_src[i]] + adn;
    e = e > 0.f ? e : NEG_SLOPE * e;
    m = fmaxf(m, e);
  }
#pragma unroll
  for (int off = 32; off; off >>= 1) m = fmaxf(m, __shfl_xor(m, off));

  float ssum = 0.f;
  for (int i = r0 + lane; i < r1; i += 64) {
    float e = as_[csr_src[i]] + adn;
    e = e > 0.f ? e : NEG_SLOPE * e;
    ssum += __expf(e - m);
  }
#pragma unroll
  for (int off = 32; off; off >>= 1) ssum += __shfl_xor(ssum, off);
  float inv = 1.f / ssum;

  const int cbase = lane * VPL;
  float acc[VPL];
#pragma unroll
  for (int v = 0; v < VPL; v++) acc[v] = 0.f;
  for (int k = r0; k < r1; k++) {
    int s = csr_src[k];  // wave-uniform -> broadcast load
    float e = as_[s] + adn;
    e = e > 0.f ? e : NEG_SLOPE * e;
    float w = __expf(e - m);
    const unsigned short* hrow = h + (int64_t)s * F + cbase;
    unsigned short uv[VPL];
    if (VPL == 4) *(ushort4v*)uv = *(const ushort4v*)hrow;
    else          *(ushort2v*)uv = *(const ushort2v*)hrow;
#pragma unroll
    for (int v = 0; v < VPL; v++) acc[v] += w * b2f(uv[v]);
  }
  float ov[VPL];
#pragma unroll
  for (int v = 0; v < VPL; v++) {
    float o = acc[v] * inv + bias[cbase + v];
    if (do_relu) o = fmaxf(o, 0.f);
    ov[v] = o;
  }
  float* op = out + (int64_t)wid * F + cbase;
  if (VPL == 4) *(f32x4*)op = *(f32x4*)ov;
  else          *(f32x2*)op = *(f32x2*)ov;
}

// ---------------- layer 3: GEMM (K x 2) + alpha3, wave per row ----------------

__global__ __launch_bounds__(256) void gemm3_kernel(const float* __restrict__ h,
                                                    const float* __restrict__ W3,
                                                    const float* __restrict__ a3s,
                                                    const float* __restrict__ a3d,
                                                    float* __restrict__ h3,
                                                    float* __restrict__ as_,
                                                    float* __restrict__ ad_,
                                                    int N, int K) {
  int wid = (blockIdx.x * 256 + threadIdx.x) >> 6;
  int lane = threadIdx.x & 63;
  if (wid >= N) return;
  float c0 = 0.f, c1 = 0.f;
  for (int k = lane; k < K; k += 64) {
    float v = h[(int64_t)wid * K + k];
    c0 += v * W3[k * 2 + 0];
    c1 += v * W3[k * 2 + 1];
  }
#pragma unroll
  for (int off = 32; off; off >>= 1) {
    c0 += __shfl_down(c0, off);
    c1 += __shfl_down(c1, off);
  }
  if (lane == 0) {
    h3[wid * 2 + 0] = c0;
    h3[wid * 2 + 1] = c1;
    as_[wid] = c0 * a3s[0] + c1 * a3s[1];
    ad_[wid] = c0 * a3d[0] + c1 * a3d[1];
  }
}

// ---------------- layer 3 aggregate + bias + final 2-class softmax ----------------

__global__ __launch_bounds__(256) void agg3_kernel(const float* __restrict__ h3,
                                                   const float* __restrict__ as_,
                                                   const float* __restrict__ ad_,
                                                   const int* __restrict__ rowstart,
                                                   const int* __restrict__ csr_src,
                                                   const float* __restrict__ b3,
                                                   float* __restrict__ out, int N) {
  int wid = (blockIdx.x * 256 + threadIdx.x) >> 6;
  int lane = threadIdx.x & 63;
  if (wid >= N) return;
  int r0 = rowstart[wid], r1 = rowstart[wid + 1];
  float adn = ad_[wid];

  float m = -1e30f;
  for (int i = r0 + lane; i < r1; i += 64) {
    float e = as_[csr_src[i]] + adn;
    e = e > 0.f ? e : NEG_SLOPE * e;
    m = fmaxf(m, e);
  }
#pragma unroll
  for (int off = 32; off; off >>= 1) m = fmaxf(m, __shfl_xor(m, off));

  float ssum = 0.f, a0 = 0.f, a1 = 0.f;
  for (int i = r0 + lane; i < r1; i += 64) {
    int s = csr_src[i];
    float e = as_[s] + adn;
    e = e > 0.f ? e : NEG_SLOPE * e;
    float w = __expf(e - m);
    ssum += w;
    a0 += w * h3[s * 2 + 0];
    a1 += w * h3[s * 2 + 1];
  }
#pragma unroll
  for (int off = 32; off; off >>= 1) {
    ssum += __shfl_xor(ssum, off);
    a0 += __shfl_xor(a0, off);
    a1 += __shfl_xor(a1, off);
  }
  if (lane == 0) {
    float inv = 1.f / ssum;
    float o0 = a0 * inv + b3[0];
    float o1 = a1 * inv + b3[1];
    float mm = fmaxf(o0, o1);
    float e0 = __expf(o0 - mm), e1 = __expf(o1 - mm);
    float d = e0 + e1;
    out[wid * 2 + 0] = e0 / d;
    out[wid * 2 + 1] = e1 / d;
  }
}

// ---------------- launcher ----------------

extern "C" void kernel_launch(void* const* d_in, const int* in_sizes, int n_in,
                              void* d_out, int out_size, void* d_ws, size_t ws_size,
                              hipStream_t stream) {
  const float* x   = (const float*)d_in[0];
  const int*   ei  = (const int*)d_in[1];
  const float* W1  = (const float*)d_in[3];
  const float* a1s = (const float*)d_in[4];
  const float* a1d = (const float*)d_in[5];
  const float* b1  = (const float*)d_in[6];
  const float* W2  = (const float*)d_in[7];
  const float* a2s = (const float*)d_in[8];
  const float* a2d = (const float*)d_in[9];
  const float* b2  = (const float*)d_in[10];
  const float* W3  = (const float*)d_in[11];
  const float* a3s = (const float*)d_in[12];
  const float* a3d = (const float*)d_in[13];
  const float* b3  = (const float*)d_in[14];

  int N   = in_sizes[2];
  int E   = in_sizes[1] / 2;
  int FIN = in_sizes[0] / N;    // 784
  int d1  = in_sizes[4];        // 128
  int d2  = in_sizes[8];        // 256
  int Kp1 = ((FIN + 31) / 32) * 32;  // 800

  // workspace carve
  char* p = (char*)d_ws;
  unsigned short* hbuf = (unsigned short*)p; p += (size_t)N * d2 * sizeof(float);
  float* buf2 = (float*)p; p += (size_t)N * d2 * sizeof(float);
  float* h3   = (float*)p; p += (size_t)N * 2 * sizeof(float);
  float* as_  = (float*)p; p += (size_t)N * sizeof(float);
  float* ad_  = (float*)p; p += (size_t)N * sizeof(float);
  int* deg      = (int*)p; p += (size_t)N * sizeof(int);
  int* rowstart = (int*)p; p += (size_t)(N + 1) * sizeof(int);
  int* cursor   = (int*)p; p += (size_t)N * sizeof(int);
  int* bsum     = (int*)p; p += 1024 * sizeof(int);
  int* csr      = (int*)p; p += (size_t)(E + N) * sizeof(int);
  p = (char*)(((uintptr_t)p + 255) & ~(uintptr_t)255);
  short* w1h = (short*)p; p += (size_t)d1 * Kp1 * sizeof(short);
  short* w1l = (short*)p; p += (size_t)d1 * Kp1 * sizeof(short);
  short* w2h = (short*)p; p += (size_t)d2 * d1 * sizeof(short);
  short* w2l = (short*)p; p += (size_t)d2 * d1 * sizeof(short);

  // CSR build (multi-block scan; nb<=256 requires N<=262144)
  hipMemsetAsync(deg, 0, (size_t)N * sizeof(int), stream);
  int tot = E + N;
  hist_kernel<<<(tot + 255) / 256, 256, 0, stream>>>(ei, deg, E, N);
  int nb = (N + 1023) / 1024;
  scan_phaseA<<<nb, 256, 0, stream>>>(deg, bsum, N);
  scan_phaseB<<<1, 256, 0, stream>>>(bsum, rowstart, nb, N);
  scan_phaseC<<<nb, 256, 0, stream>>>(deg, bsum, rowstart, cursor, N);
  scatter_kernel<<<(tot + 255) / 256, 256, 0, stream>>>(ei, cursor, csr, E, N);

  // weight transpose+split (tiny)
  convw_kernel<<<(d1 * Kp1 + 255) / 256, 256, 0, stream>>>(W1, w1h, w1l, FIN, d1, Kp1);
  convw_kernel<<<(d2 * d1 + 255) / 256, 256, 0, stream>>>(W2, w2h, w2l, d1, d2, d1);

  int wb = (N + 3) / 4;  // wave-per-node, 4 waves/block

  // layer 1: x@W1 -> hbuf bf16 [N,128]; agg -> buf2 fp32 (relu)
  {
    dim3 g((N + 127) / 128, d1 / 128);
    mfma_gemm_split<<<g, 256, 0, stream>>>(x, w1h, w1l, hbuf, N, d1, FIN, Kp1);
    alpha_kernel<<<wb, 256, 0, stream>>>(hbuf, a1s, a1d, as_, ad_, N, d1);
    agg_kernel<2><<<wb, 256, 0, stream>>>(hbuf, as_, ad_, rowstart, csr, b1, buf2, N, d1, 1);
  }
  // layer 2: buf2@W2 -> hbuf bf16 [N,256]; agg -> buf2 fp32 (relu)
  {
    dim3 g((N + 127) / 128, d2 / 128);
    mfma_gemm_split<<<g, 256, 0, stream>>>(buf2, w2h, w2l, hbuf, N, d2, d1, d1);
    alpha_kernel<<<wb, 256, 0, stream>>>(hbuf, a2s, a2d, as_, ad_, N, d2);
    agg_kernel<4><<<wb, 256, 0, stream>>>(hbuf, as_, ad_, rowstart, csr, b2, buf2, N, d2, 1);
  }
  // layer 3: buf2@W3 -> h3 [N,2]; agg + bias + softmax -> d_out
  {
    gemm3_kernel<<<wb, 256, 0, stream>>>(buf2, W3, a3s, a3d, h3, as_, ad_, N, d2);
    agg3_kernel<<<wb, 256, 0, stream>>>(h3, as_, ad_, rowstart, csr, b3, (float*)d_out, N);
  }
}

// Round 5
// 1073.069 us; speedup vs baseline: 1.8473x; 1.1729x over previous
//
#include <hip/hip_runtime.h>
#include <cstdint>

#define NEG_SLOPE 0.2f

typedef __attribute__((ext_vector_type(8))) short short8;     // 8 bf16 = 4 VGPRs
typedef __attribute__((ext_vector_type(4))) float f32x4;
typedef __attribute__((ext_vector_type(2))) float f32x2;
typedef __attribute__((ext_vector_type(4))) unsigned short ushort4v;
typedef __attribute__((ext_vector_type(2))) unsigned short ushort2v;

// split fp32 v into bf16 hi + bf16 lo (truncation; hi+lo ~ v to ~2^-16 rel)
__device__ inline void split_bf16(float v, short& hi, short& lo) {
  unsigned u = __builtin_bit_cast(unsigned, v);
  hi = (short)(u >> 16);
  float hif = __builtin_bit_cast(float, u & 0xffff0000u);
  float r = v - hif;
  lo = (short)(__builtin_bit_cast(unsigned, r) >> 16);
}

__device__ inline float b2f(unsigned short u) {
  return __builtin_bit_cast(float, (unsigned)u << 16);
}
__device__ inline unsigned short f2b_rne(float f) {
  unsigned u = __builtin_bit_cast(unsigned, f);
  return (unsigned short)((u + 0x7fffu + ((u >> 16) & 1u)) >> 16);
}
__device__ inline float leaky(float e) { return e > 0.f ? e : NEG_SLOPE * e; }

// ---------------- CSR build ----------------

__global__ __launch_bounds__(256) void hist_kernel(const int* __restrict__ ei,
                                                   int* __restrict__ deg, int E, int N) {
  int e = blockIdx.x * 256 + threadIdx.x;
  int total = E + N;
  if (e >= total) return;
  int d = (e < E) ? ei[E + e] : (e - E);   // self-loop for virtual edges
  atomicAdd(&deg[d], 1);
}

// ---- 3-phase device-wide exclusive scan of deg[0..n) (chunk=1024/block; n<=262144) ----

__global__ __launch_bounds__(256) void scan_phaseA(const int* __restrict__ deg,
                                                   int* __restrict__ bsum, int n) {
  __shared__ int red[256];
  int base = blockIdx.x * 1024;
  int s = 0;
#pragma unroll
  for (int j = 0; j < 4; j++) {
    int i = base + threadIdx.x + j * 256;
    if (i < n) s += deg[i];
  }
  red[threadIdx.x] = s;
  __syncthreads();
  for (int off = 128; off; off >>= 1) {
    if (threadIdx.x < off) red[threadIdx.x] += red[threadIdx.x + off];
    __syncthreads();
  }
  if (threadIdx.x == 0) bsum[blockIdx.x] = red[0];
}

__global__ __launch_bounds__(256) void scan_phaseB(int* __restrict__ bsum,
                                                   int* __restrict__ rowstart,
                                                   int nb, int n) {
  __shared__ int sc[256];
  int tid = threadIdx.x;
  int v = (tid < nb) ? bsum[tid] : 0;
  sc[tid] = v;
  __syncthreads();
  for (int off = 1; off < 256; off <<= 1) {
    int t = (tid >= off) ? sc[tid - off] : 0;
    __syncthreads();
    sc[tid] += t;
    __syncthreads();
  }
  if (tid < nb) bsum[tid] = sc[tid] - v;   // exclusive block offsets
  if (tid == 0) rowstart[n] = sc[255];     // grand total
}

__global__ __launch_bounds__(256) void scan_phaseC(const int* __restrict__ deg,
                                                   const int* __restrict__ bsum,
                                                   int* __restrict__ rowstart,
                                                   int* __restrict__ cursor, int n) {
  __shared__ int tsum[256];
  int tid = threadIdx.x;
  int base = blockIdx.x * 1024 + tid * 4;  // 4 contiguous per thread
  int d[4];
  int s = 0;
#pragma unroll
  for (int j = 0; j < 4; j++) {
    int i = base + j;
    d[j] = (i < n) ? deg[i] : 0;
    s += d[j];
  }
  tsum[tid] = s;
  __syncthreads();
  for (int off = 1; off < 256; off <<= 1) {
    int t = (tid >= off) ? tsum[tid - off] : 0;
    __syncthreads();
    tsum[tid] += t;
    __syncthreads();
  }
  int run = bsum[blockIdx.x] + tsum[tid] - s;  // exclusive prefix for this thread
#pragma unroll
  for (int j = 0; j < 4; j++) {
    int i = base + j;
    if (i < n) { rowstart[i] = run; cursor[i] = run; }
    run += d[j];
  }
}

__global__ __launch_bounds__(256) void scatter_kernel(const int* __restrict__ ei,
                                                      int* __restrict__ cursor,
                                                      int* __restrict__ csr_src, int E, int N) {
  int e = blockIdx.x * 256 + threadIdx.x;
  int total = E + N;
  if (e >= total) return;
  int s, d;
  if (e < E) { s = ei[e]; d = ei[E + e]; }
  else       { s = e - E; d = e - E; }
  int p = atomicAdd(&cursor[d], 1);
  csr_src[p] = s;
}

// ---------------- weight convert: W[K][N] fp32 -> Wt_hi/Wt_lo [N][Kp] bf16, zero-pad ----

__global__ __launch_bounds__(256) void convw_kernel(const float* __restrict__ W,
                                                    short* __restrict__ Whi,
                                                    short* __restrict__ Wlo,
                                                    int K, int N, int Kp) {
  int idx = blockIdx.x * 256 + threadIdx.x;
  if (idx >= N * Kp) return;
  int n = idx / Kp, k = idx % Kp;
  float v = (k < K) ? W[(size_t)k * N + n] : 0.f;
  short hi, lo;
  split_bf16(v, hi, lo);
  Whi[idx] = hi;
  Wlo[idx] = lo;
}

// ---------------- split-bf16 MFMA GEMM: C[M][Nn](bf16) = A[M][K](f32) @ Wt^T ----------------

#define LDK 40   // padded LDS k-stride: 80B rows -> uniform 2-way bank aliasing (free, m136)

__global__ __launch_bounds__(256, 2) void mfma_gemm_split(
    const float* __restrict__ A, const short* __restrict__ Bhi, const short* __restrict__ Blo,
    unsigned short* __restrict__ C, int M, int Nn, int K, int Kp) {
  __shared__ short Ah[128 * LDK], Al[128 * LDK], Bh[128 * LDK], Bl[128 * LDK];

  const int t = threadIdx.x;
  const int bm = blockIdx.x * 128;
  const int n0 = blockIdx.y * 128;

  const int srow = t >> 1;        // staging row 0..127
  const int shalf = t & 1;        // which 16-elem half of the 32-k tile
  const bool arow_ok = (bm + srow) < M;

  const int w = t >> 6, lane = t & 63;
  const int wm = (w >> 1) * 64, wn = (w & 1) * 64;  // wave's 64x64 quadrant
  const int lm = lane & 15, quad = lane >> 4;

  f32x4 acc[4][4];
#pragma unroll
  for (int i = 0; i < 4; i++)
#pragma unroll
    for (int j = 0; j < 4; j++) acc[i][j] = (f32x4)(0.f);

  for (int k0 = 0; k0 < Kp; k0 += 32) {
    __syncthreads();

    // --- stage A: load 16 fp32, split to hi/lo bf16 ---
    {
      const int kbase = k0 + shalf * 16;
      f32x4 v0 = (f32x4)(0.f), v1 = (f32x4)(0.f), v2 = (f32x4)(0.f), v3 = (f32x4)(0.f);
      if (arow_ok && kbase < K) {   // K % 16 == 0 -> chunk fully in or out
        const f32x4* p = (const f32x4*)(A + (size_t)(bm + srow) * K + kbase);
        v0 = p[0]; v1 = p[1]; v2 = p[2]; v3 = p[3];
      }
      float f[16] = {v0[0], v0[1], v0[2], v0[3], v1[0], v1[1], v1[2], v1[3],
                     v2[0], v2[1], v2[2], v2[3], v3[0], v3[1], v3[2], v3[3]};
      short hi[16], lo[16];
#pragma unroll
      for (int j = 0; j < 16; j++) split_bf16(f[j], hi[j], lo[j]);
      const int la = srow * LDK + shalf * 16;
      *(short8*)&Ah[la] = *(short8*)&hi[0];
      *(short8*)&Ah[la + 8] = *(short8*)&hi[8];
      *(short8*)&Al[la] = *(short8*)&lo[0];
      *(short8*)&Al[la + 8] = *(short8*)&lo[8];
    }
    // --- stage B ---
    {
      const size_t gb = (size_t)(n0 + srow) * Kp + k0 + shalf * 16;
      const short8* ph = (const short8*)(Bhi + gb);
      const short8* pl = (const short8*)(Blo + gb);
      short8 h0 = ph[0], h1 = ph[1], l0 = pl[0], l1 = pl[1];
      const int la = srow * LDK + shalf * 16;
      *(short8*)&Bh[la] = h0;
      *(short8*)&Bh[la + 8] = h1;
      *(short8*)&Bl[la] = l0;
      *(short8*)&Bl[la + 8] = l1;
    }
    __syncthreads();

    // --- fragments + 48 MFMAs ---
    short8 afh[4], afl[4], bfh[4], bfl[4];
#pragma unroll
    for (int i = 0; i < 4; i++) {
      const int ra = (wm + i * 16 + lm) * LDK + quad * 8;
      afh[i] = *(const short8*)&Ah[ra];
      afl[i] = *(const short8*)&Al[ra];
      const int rb = (wn + i * 16 + lm) * LDK + quad * 8;
      bfh[i] = *(const short8*)&Bh[rb];
      bfl[i] = *(const short8*)&Bl[rb];
    }
#pragma unroll
    for (int i = 0; i < 4; i++)
#pragma unroll
      for (int j = 0; j < 4; j++) {
        acc[i][j] = __builtin_amdgcn_mfma_f32_16x16x32_bf16(afh[i], bfh[j], acc[i][j], 0, 0, 0);
        acc[i][j] = __builtin_amdgcn_mfma_f32_16x16x32_bf16(afh[i], bfl[j], acc[i][j], 0, 0, 0);
        acc[i][j] = __builtin_amdgcn_mfma_f32_16x16x32_bf16(afl[i], bfh[j], acc[i][j], 0, 0, 0);
      }
  }

  // --- epilogue: C/D layout col=lane&15, row=quad*4+reg; write bf16 (RNE) ---
#pragma unroll
  for (int i = 0; i < 4; i++) {
    const int rbase = bm + wm + i * 16 + quad * 4;
#pragma unroll
    for (int j = 0; j < 4; j++) {
      const int c = n0 + wn + j * 16 + lm;
#pragma unroll
      for (int r = 0; r < 4; r++) {
        const int row = rbase + r;
        if (row < M) C[(size_t)row * Nn + c] = f2b_rne(acc[i][j][r]);
      }
    }
  }
}

// ---------------- alpha dot products from bf16 h (ushort4 vector loads) ----------------

__global__ __launch_bounds__(256) void alpha_kernel(const unsigned short* __restrict__ h,
                                                    const float* __restrict__ a_s,
                                                    const float* __restrict__ a_d,
                                                    float* __restrict__ as_,
                                                    float* __restrict__ ad_,
                                                    int N, int F) {
  int wid = (blockIdx.x * 256 + threadIdx.x) >> 6;
  int lane = threadIdx.x & 63;
  if (wid >= N) return;
  float ss = 0.f, dd = 0.f;
  for (int c = lane * 4; c < F; c += 256) {
    ushort4v uv = *(const ushort4v*)(h + (int64_t)wid * F + c);
#pragma unroll
    for (int v = 0; v < 4; v++) {
      float x = b2f(uv[v]);
      ss += x * a_s[c + v];
      dd += x * a_d[c + v];
    }
  }
#pragma unroll
  for (int off = 32; off; off >>= 1) {
    ss += __shfl_down(ss, off);
    dd += __shfl_down(dd, off);
  }
  if (lane == 0) { as_[wid] = ss; ad_[wid] = dd; }
}

// ---------------- per-node edge softmax + aggregate + bias (+relu), bf16 gather ----------------
// online softmax (1 random sweep) + gather pass unrolled x4 for MLP

template <int VPL>
__global__ __launch_bounds__(256) void agg_kernel(const unsigned short* __restrict__ h,
                                                  const float* __restrict__ as_,
                                                  const float* __restrict__ ad_,
                                                  const int* __restrict__ rowstart,
                                                  const int* __restrict__ csr_src,
                                                  const float* __restrict__ bias,
                                                  float* __restrict__ out,
                                                  int N, int F, int do_relu) {
  int wid = (blockIdx.x * 256 + threadIdx.x) >> 6;
  int lane = threadIdx.x & 63;
  if (wid >= N) return;
  int r0 = rowstart[wid], r1 = rowstart[wid + 1];
  float adn = ad_[wid];

  // fused online-softmax pass: lane-local (m, ssum), then butterfly combine
  float m = -1e30f, ssum = 0.f;
  for (int i = r0 + lane; i < r1; i += 64) {
    float e = leaky(as_[csr_src[i]] + adn);
    float mn = fmaxf(m, e);
    ssum = ssum * __expf(m - mn) + __expf(e - mn);
    m = mn;
  }
#pragma unroll
  for (int off = 32; off; off >>= 1) {
    float mo = __shfl_xor(m, off);
    float so = __shfl_xor(ssum, off);
    float mn = fmaxf(m, mo);
    ssum = ssum * __expf(m - mn) + so * __expf(mo - mn);
    m = mn;
  }
  float inv = 1.f / ssum;

  // gather pass: unroll x4 edges -> 4 row-loads in flight
  const int cbase = lane * VPL;
  float acc[VPL];
#pragma unroll
  for (int v = 0; v < VPL; v++) acc[v] = 0.f;

  int k = r0;
  for (; k + 4 <= r1; k += 4) {
    int s0 = csr_src[k], s1 = csr_src[k + 1], s2 = csr_src[k + 2], s3 = csr_src[k + 3];
    float w0 = __expf(leaky(as_[s0] + adn) - m);
    float w1 = __expf(leaky(as_[s1] + adn) - m);
    float w2 = __expf(leaky(as_[s2] + adn) - m);
    float w3 = __expf(leaky(as_[s3] + adn) - m);
    unsigned short u0[VPL], u1[VPL], u2[VPL], u3[VPL];
    if (VPL == 4) {
      *(ushort4v*)u0 = *(const ushort4v*)(h + (int64_t)s0 * F + cbase);
      *(ushort4v*)u1 = *(const ushort4v*)(h + (int64_t)s1 * F + cbase);
      *(ushort4v*)u2 = *(const ushort4v*)(h + (int64_t)s2 * F + cbase);
      *(ushort4v*)u3 = *(const ushort4v*)(h + (int64_t)s3 * F + cbase);
    } else {
      *(ushort2v*)u0 = *(const ushort2v*)(h + (int64_t)s0 * F + cbase);
      *(ushort2v*)u1 = *(const ushort2v*)(h + (int64_t)s1 * F + cbase);
      *(ushort2v*)u2 = *(const ushort2v*)(h + (int64_t)s2 * F + cbase);
      *(ushort2v*)u3 = *(const ushort2v*)(h + (int64_t)s3 * F + cbase);
    }
#pragma unroll
    for (int v = 0; v < VPL; v++)
      acc[v] += w0 * b2f(u0[v]) + w1 * b2f(u1[v]) + w2 * b2f(u2[v]) + w3 * b2f(u3[v]);
  }
  for (; k < r1; k++) {
    int s = csr_src[k];
    float w = __expf(leaky(as_[s] + adn) - m);
    const unsigned short* hrow = h + (int64_t)s * F + cbase;
    unsigned short uv[VPL];
    if (VPL == 4) *(ushort4v*)uv = *(const ushort4v*)hrow;
    else          *(ushort2v*)uv = *(const ushort2v*)hrow;
#pragma unroll
    for (int v = 0; v < VPL; v++) acc[v] += w * b2f(uv[v]);
  }

  float ov[VPL];
#pragma unroll
  for (int v = 0; v < VPL; v++) {
    float o = acc[v] * inv + bias[cbase + v];
    if (do_relu) o = fmaxf(o, 0.f);
    ov[v] = o;
  }
  float* op = out + (int64_t)wid * F + cbase;
  if (VPL == 4) *(f32x4*)op = *(f32x4*)ov;
  else          *(f32x2*)op = *(f32x2*)ov;
}

// ---------------- layer 3: GEMM (K x 2) + alpha3, wave per row ----------------

__global__ __launch_bounds__(256) void gemm3_kernel(const float* __restrict__ h,
                                                    const float* __restrict__ W3,
                                                    const float* __restrict__ a3s,
                                                    const float* __restrict__ a3d,
                                                    float* __restrict__ h3,
                                                    float* __restrict__ as_,
                                                    float* __restrict__ ad_,
                                                    int N, int K) {
  int wid = (blockIdx.x * 256 + threadIdx.x) >> 6;
  int lane = threadIdx.x & 63;
  if (wid >= N) return;
  float c0 = 0.f, c1 = 0.f;
  for (int k = lane; k < K; k += 64) {
    float v = h[(int64_t)wid * K + k];
    c0 += v * W3[k * 2 + 0];
    c1 += v * W3[k * 2 + 1];
  }
#pragma unroll
  for (int off = 32; off; off >>= 1) {
    c0 += __shfl_down(c0, off);
    c1 += __shfl_down(c1, off);
  }
  if (lane == 0) {
    h3[wid * 2 + 0] = c0;
    h3[wid * 2 + 1] = c1;
    as_[wid] = c0 * a3s[0] + c1 * a3s[1];
    ad_[wid] = c0 * a3d[0] + c1 * a3d[1];
  }
}

// ---------------- layer 3 aggregate + bias + final 2-class softmax ----------------

__global__ __launch_bounds__(256) void agg3_kernel(const float* __restrict__ h3,
                                                   const float* __restrict__ as_,
                                                   const float* __restrict__ ad_,
                                                   const int* __restrict__ rowstart,
                                                   const int* __restrict__ csr_src,
                                                   const float* __restrict__ b3,
                                                   float* __restrict__ out, int N) {
  int wid = (blockIdx.x * 256 + threadIdx.x) >> 6;
  int lane = threadIdx.x & 63;
  if (wid >= N) return;
  int r0 = rowstart[wid], r1 = rowstart[wid + 1];
  float adn = ad_[wid];

  float m = -1e30f;
  for (int i = r0 + lane; i < r1; i += 64) {
    float e = leaky(as_[csr_src[i]] + adn);
    m = fmaxf(m, e);
  }
#pragma unroll
  for (int off = 32; off; off >>= 1) m = fmaxf(m, __shfl_xor(m, off));

  float ssum = 0.f, a0 = 0.f, a1 = 0.f;
  for (int i = r0 + lane; i < r1; i += 64) {
    int s = csr_src[i];
    float e = leaky(as_[s] + adn);
    float w = __expf(e - m);
    ssum += w;
    a0 += w * h3[s * 2 + 0];
    a1 += w * h3[s * 2 + 1];
  }
#pragma unroll
  for (int off = 32; off; off >>= 1) {
    ssum += __shfl_xor(ssum, off);
    a0 += __shfl_xor(a0, off);
    a1 += __shfl_xor(a1, off);
  }
  if (lane == 0) {
    float inv = 1.f / ssum;
    float o0 = a0 * inv + b3[0];
    float o1 = a1 * inv + b3[1];
    float mm = fmaxf(o0, o1);
    float e0 = __expf(o0 - mm), e1 = __expf(o1 - mm);
    float d = e0 + e1;
    out[wid * 2 + 0] = e0 / d;
    out[wid * 2 + 1] = e1 / d;
  }
}

// ---------------- launcher ----------------

extern "C" void kernel_launch(void* const* d_in, const int* in_sizes, int n_in,
                              void* d_out, int out_size, void* d_ws, size_t ws_size,
                              hipStream_t stream) {
  const float* x   = (const float*)d_in[0];
  const int*   ei  = (const int*)d_in[1];
  const float* W1  = (const float*)d_in[3];
  const float* a1s = (const float*)d_in[4];
  const float* a1d = (const float*)d_in[5];
  const float* b1  = (const float*)d_in[6];
  const float* W2  = (const float*)d_in[7];
  const float* a2s = (const float*)d_in[8];
  const float* a2d = (const float*)d_in[9];
  const float* b2  = (const float*)d_in[10];
  const float* W3  = (const float*)d_in[11];
  const float* a3s = (const float*)d_in[12];
  const float* a3d = (const float*)d_in[13];
  const float* b3  = (const float*)d_in[14];

  int N   = in_sizes[2];
  int E   = in_sizes[1] / 2;
  int FIN = in_sizes[0] / N;    // 784
  int d1  = in_sizes[4];        // 128
  int d2  = in_sizes[8];        // 256
  int Kp1 = ((FIN + 31) / 32) * 32;  // 800

  // workspace carve
  char* p = (char*)d_ws;
  unsigned short* hbuf = (unsigned short*)p; p += (size_t)N * d2 * sizeof(float);
  float* buf2 = (float*)p; p += (size_t)N * d2 * sizeof(float);
  float* h3   = (float*)p; p += (size_t)N * 2 * sizeof(float);
  float* as_  = (float*)p; p += (size_t)N * sizeof(float);
  float* ad_  = (float*)p; p += (size_t)N * sizeof(float);
  int* deg      = (int*)p; p += (size_t)N * sizeof(int);
  int* rowstart = (int*)p; p += (size_t)(N + 1) * sizeof(int);
  int* cursor   = (int*)p; p += (size_t)N * sizeof(int);
  int* bsum     = (int*)p; p += 1024 * sizeof(int);
  int* csr      = (int*)p; p += (size_t)(E + N) * sizeof(int);
  p = (char*)(((uintptr_t)p + 255) & ~(uintptr_t)255);
  short* w1h = (short*)p; p += (size_t)d1 * Kp1 * sizeof(short);
  short* w1l = (short*)p; p += (size_t)d1 * Kp1 * sizeof(short);
  short* w2h = (short*)p; p += (size_t)d2 * d1 * sizeof(short);
  short* w2l = (short*)p; p += (size_t)d2 * d1 * sizeof(short);

  // CSR build (multi-block scan; nb<=256 requires N<=262144)
  hipMemsetAsync(deg, 0, (size_t)N * sizeof(int), stream);
  int tot = E + N;
  hist_kernel<<<(tot + 255) / 256, 256, 0, stream>>>(ei, deg, E, N);
  int nb = (N + 1023) / 1024;
  scan_phaseA<<<nb, 256, 0, stream>>>(deg, bsum, N);
  scan_phaseB<<<1, 256, 0, stream>>>(bsum, rowstart, nb, N);
  scan_phaseC<<<nb, 256, 0, stream>>>(deg, bsum, rowstart, cursor, N);
  scatter_kernel<<<(tot + 255) / 256, 256, 0, stream>>>(ei, cursor, csr, E, N);

  // weight transpose+split (tiny)
  convw_kernel<<<(d1 * Kp1 + 255) / 256, 256, 0, stream>>>(W1, w1h, w1l, FIN, d1, Kp1);
  convw_kernel<<<(d2 * d1 + 255) / 256, 256, 0, stream>>>(W2, w2h, w2l, d1, d2, d1);

  int wb = (N + 3) / 4;  // wave-per-node, 4 waves/block

  // layer 1: x@W1 -> hbuf bf16 [N,128]; agg -> buf2 fp32 (relu)
  {
    dim3 g((N + 127) / 128, d1 / 128);
    mfma_gemm_split<<<g, 256, 0, stream>>>(x, w1h, w1l, hbuf, N, d1, FIN, Kp1);
    alpha_kernel<<<wb, 256, 0, stream>>>(hbuf, a1s, a1d, as_, ad_, N, d1);
    agg_kernel<2><<<wb, 256, 0, stream>>>(hbuf, as_, ad_, rowstart, csr, b1, buf2, N, d1, 1);
  }
  // layer 2: buf2@W2 -> hbuf bf16 [N,256]; agg -> buf2 fp32 (relu)
  {
    dim3 g((N + 127) / 128, d2 / 128);
    mfma_gemm_split<<<g, 256, 0, stream>>>(buf2, w2h, w2l, hbuf, N, d2, d1, d1);
    alpha_kernel<<<wb, 256, 0, stream>>>(hbuf, a2s, a2d, as_, ad_, N, d2);
    agg_kernel<4><<<wb, 256, 0, stream>>>(hbuf, as_, ad_, rowstart, csr, b2, buf2, N, d2, 1);
  }
  // layer 3: buf2@W3 -> h3 [N,2]; agg + bias + softmax -> d_out
  {
    gemm3_kernel<<<wb, 256, 0, stream>>>(buf2, W3, a3s, a3d, h3, as_, ad_, N, d2);
    agg3_kernel<<<wb, 256, 0, stream>>>(h3, as_, ad_, rowstart, csr, b3, (float*)d_out, N);
  }
}

// Round 6
// 1052.485 us; speedup vs baseline: 1.8835x; 1.0196x over previous
//
#include <hip/hip_runtime.h>
#include <cstdint>

#define NEG_SLOPE 0.2f

typedef __attribute__((ext_vector_type(8))) short short8;     // 8 bf16 = 4 VGPRs
typedef __attribute__((ext_vector_type(4))) float f32x4;
typedef __attribute__((ext_vector_type(2))) float f32x2;
typedef __attribute__((ext_vector_type(4))) unsigned short ushort4v;
typedef __attribute__((ext_vector_type(2))) unsigned short ushort2v;

// split fp32 v into bf16 hi + bf16 lo (truncation; hi+lo ~ v to ~2^-16 rel)
__device__ inline void split_bf16(float v, short& hi, short& lo) {
  unsigned u = __builtin_bit_cast(unsigned, v);
  hi = (short)(u >> 16);
  float hif = __builtin_bit_cast(float, u & 0xffff0000u);
  float r = v - hif;
  lo = (short)(__builtin_bit_cast(unsigned, r) >> 16);
}

__device__ inline float b2f(unsigned short u) {
  return __builtin_bit_cast(float, (unsigned)u << 16);
}
__device__ inline unsigned short f2b_rne(float f) {
  unsigned u = __builtin_bit_cast(unsigned, f);
  return (unsigned short)((u + 0x7fffu + ((u >> 16) & 1u)) >> 16);
}
__device__ inline float leaky(float e) { return e > 0.f ? e : NEG_SLOPE * e; }

// ---------------- CSR build ----------------

__global__ __launch_bounds__(256) void hist_kernel(const int* __restrict__ ei,
                                                   int* __restrict__ deg, int E, int N) {
  int e = blockIdx.x * 256 + threadIdx.x;
  int total = E + N;
  if (e >= total) return;
  int d = (e < E) ? ei[E + e] : (e - E);   // self-loop for virtual edges
  atomicAdd(&deg[d], 1);
}

// ---- 3-phase device-wide exclusive scan of deg[0..n) (chunk=1024/block; n<=262144) ----

__global__ __launch_bounds__(256) void scan_phaseA(const int* __restrict__ deg,
                                                   int* __restrict__ bsum, int n) {
  __shared__ int red[256];
  int base = blockIdx.x * 1024;
  int s = 0;
#pragma unroll
  for (int j = 0; j < 4; j++) {
    int i = base + threadIdx.x + j * 256;
    if (i < n) s += deg[i];
  }
  red[threadIdx.x] = s;
  __syncthreads();
  for (int off = 128; off; off >>= 1) {
    if (threadIdx.x < off) red[threadIdx.x] += red[threadIdx.x + off];
    __syncthreads();
  }
  if (threadIdx.x == 0) bsum[blockIdx.x] = red[0];
}

__global__ __launch_bounds__(256) void scan_phaseB(int* __restrict__ bsum,
                                                   int* __restrict__ rowstart,
                                                   int nb, int n) {
  __shared__ int sc[256];
  int tid = threadIdx.x;
  int v = (tid < nb) ? bsum[tid] : 0;
  sc[tid] = v;
  __syncthreads();
  for (int off = 1; off < 256; off <<= 1) {
    int t = (tid >= off) ? sc[tid - off] : 0;
    __syncthreads();
    sc[tid] += t;
    __syncthreads();
  }
  if (tid < nb) bsum[tid] = sc[tid] - v;   // exclusive block offsets
  if (tid == 0) rowstart[n] = sc[255];     // grand total
}

__global__ __launch_bounds__(256) void scan_phaseC(const int* __restrict__ deg,
                                                   const int* __restrict__ bsum,
                                                   int* __restrict__ rowstart,
                                                   int* __restrict__ cursor, int n) {
  __shared__ int tsum[256];
  int tid = threadIdx.x;
  int base = blockIdx.x * 1024 + tid * 4;  // 4 contiguous per thread
  int d[4];
  int s = 0;
#pragma unroll
  for (int j = 0; j < 4; j++) {
    int i = base + j;
    d[j] = (i < n) ? deg[i] : 0;
    s += d[j];
  }
  tsum[tid] = s;
  __syncthreads();
  for (int off = 1; off < 256; off <<= 1) {
    int t = (tid >= off) ? tsum[tid - off] : 0;
    __syncthreads();
    tsum[tid] += t;
    __syncthreads();
  }
  int run = bsum[blockIdx.x] + tsum[tid] - s;  // exclusive prefix for this thread
#pragma unroll
  for (int j = 0; j < 4; j++) {
    int i = base + j;
    if (i < n) { rowstart[i] = run; cursor[i] = run; }
    run += d[j];
  }
}

__global__ __launch_bounds__(256) void scatter_kernel(const int* __restrict__ ei,
                                                      int* __restrict__ cursor,
                                                      int* __restrict__ csr_src, int E, int N) {
  int e = blockIdx.x * 256 + threadIdx.x;
  int total = E + N;
  if (e >= total) return;
  int s, d;
  if (e < E) { s = ei[e]; d = ei[E + e]; }
  else       { s = e - E; d = e - E; }
  int p = atomicAdd(&cursor[d], 1);
  csr_src[p] = s;
}

// ---------------- weight convert: W[K][N] fp32 -> Wt_hi/Wt_lo [N][Kp] bf16, zero-pad ----

__global__ __launch_bounds__(256) void convw_kernel(const float* __restrict__ W,
                                                    short* __restrict__ Whi,
                                                    short* __restrict__ Wlo,
                                                    int K, int N, int Kp) {
  int idx = blockIdx.x * 256 + threadIdx.x;
  if (idx >= N * Kp) return;
  int n = idx / Kp, k = idx % Kp;
  float v = (k < K) ? W[(size_t)k * N + n] : 0.f;
  short hi, lo;
  split_bf16(v, hi, lo);
  Whi[idx] = hi;
  Wlo[idx] = lo;
}

// ---------------- 2-stream MFMA GEMM: C = round_bf16(A) @ (Bhi+Blo)^T ----------------
// A fp32 -> bf16 RNE in staging; B pre-split keeps weight precision.
// 32 MFMAs/tile, 3 LDS buffers (~31 KB).

#define LDK 40   // padded LDS k-stride: 80B rows -> uniform 2-way bank aliasing (free, m136)

__global__ __launch_bounds__(256, 3) void mfma_gemm_split(
    const float* __restrict__ A, const short* __restrict__ Bhi, const short* __restrict__ Blo,
    unsigned short* __restrict__ C, int M, int Nn, int K, int Kp) {
  __shared__ short Ah[128 * LDK], Bh[128 * LDK], Bl[128 * LDK];

  const int t = threadIdx.x;
  const int bm = blockIdx.x * 128;
  const int n0 = blockIdx.y * 128;

  const int srow = t >> 1;        // staging row 0..127
  const int shalf = t & 1;        // which 16-elem half of the 32-k tile
  const bool arow_ok = (bm + srow) < M;

  const int w = t >> 6, lane = t & 63;
  const int wm = (w >> 1) * 64, wn = (w & 1) * 64;  // wave's 64x64 quadrant
  const int lm = lane & 15, quad = lane >> 4;

  f32x4 acc[4][4];
#pragma unroll
  for (int i = 0; i < 4; i++)
#pragma unroll
    for (int j = 0; j < 4; j++) acc[i][j] = (f32x4)(0.f);

  for (int k0 = 0; k0 < Kp; k0 += 32) {
    __syncthreads();

    // --- stage A: load 16 fp32, round to bf16 (RNE) ---
    {
      const int kbase = k0 + shalf * 16;
      f32x4 v0 = (f32x4)(0.f), v1 = (f32x4)(0.f), v2 = (f32x4)(0.f), v3 = (f32x4)(0.f);
      if (arow_ok && kbase < K) {   // K % 16 == 0 -> chunk fully in or out
        const f32x4* p = (const f32x4*)(A + (size_t)(bm + srow) * K + kbase);
        v0 = p[0]; v1 = p[1]; v2 = p[2]; v3 = p[3];
      }
      float f[16] = {v0[0], v0[1], v0[2], v0[3], v1[0], v1[1], v1[2], v1[3],
                     v2[0], v2[1], v2[2], v2[3], v3[0], v3[1], v3[2], v3[3]};
      unsigned short hi[16];
#pragma unroll
      for (int j = 0; j < 16; j++) hi[j] = f2b_rne(f[j]);
      const int la = srow * LDK + shalf * 16;
      *(short8*)&Ah[la] = *(short8*)&hi[0];
      *(short8*)&Ah[la + 8] = *(short8*)&hi[8];
    }
    // --- stage B ---
    {
      const size_t gb = (size_t)(n0 + srow) * Kp + k0 + shalf * 16;
      const short8* ph = (const short8*)(Bhi + gb);
      const short8* pl = (const short8*)(Blo + gb);
      short8 h0 = ph[0], h1 = ph[1], l0 = pl[0], l1 = pl[1];
      const int la = srow * LDK + shalf * 16;
      *(short8*)&Bh[la] = h0;
      *(short8*)&Bh[la + 8] = h1;
      *(short8*)&Bl[la] = l0;
      *(short8*)&Bl[la + 8] = l1;
    }
    __syncthreads();

    // --- fragments + 32 MFMAs ---
    short8 afh[4], bfh[4], bfl[4];
#pragma unroll
    for (int i = 0; i < 4; i++) {
      const int ra = (wm + i * 16 + lm) * LDK + quad * 8;
      afh[i] = *(const short8*)&Ah[ra];
      const int rb = (wn + i * 16 + lm) * LDK + quad * 8;
      bfh[i] = *(const short8*)&Bh[rb];
      bfl[i] = *(const short8*)&Bl[rb];
    }
#pragma unroll
    for (int i = 0; i < 4; i++)
#pragma unroll
      for (int j = 0; j < 4; j++) {
        acc[i][j] = __builtin_amdgcn_mfma_f32_16x16x32_bf16(afh[i], bfh[j], acc[i][j], 0, 0, 0);
        acc[i][j] = __builtin_amdgcn_mfma_f32_16x16x32_bf16(afh[i], bfl[j], acc[i][j], 0, 0, 0);
      }
  }

  // --- epilogue: C/D layout col=lane&15, row=quad*4+reg; write bf16 (RNE) ---
#pragma unroll
  for (int i = 0; i < 4; i++) {
    const int rbase = bm + wm + i * 16 + quad * 4;
#pragma unroll
    for (int j = 0; j < 4; j++) {
      const int c = n0 + wn + j * 16 + lm;
#pragma unroll
      for (int r = 0; r < 4; r++) {
        const int row = rbase + r;
        if (row < M) C[(size_t)row * Nn + c] = f2b_rne(acc[i][j][r]);
      }
    }
  }
}

// ---------------- alpha dot products from bf16 h (ushort4 vector loads) ----------------

__global__ __launch_bounds__(256) void alpha_kernel(const unsigned short* __restrict__ h,
                                                    const float* __restrict__ a_s,
                                                    const float* __restrict__ a_d,
                                                    float* __restrict__ as_,
                                                    float* __restrict__ ad_,
                                                    int N, int F) {
  int wid = (blockIdx.x * 256 + threadIdx.x) >> 6;
  int lane = threadIdx.x & 63;
  if (wid >= N) return;
  float ss = 0.f, dd = 0.f;
  for (int c = lane * 4; c < F; c += 256) {
    ushort4v uv = *(const ushort4v*)(h + (int64_t)wid * F + c);
#pragma unroll
    for (int v = 0; v < 4; v++) {
      float x = b2f(uv[v]);
      ss += x * a_s[c + v];
      dd += x * a_d[c + v];
    }
  }
#pragma unroll
  for (int off = 32; off; off >>= 1) {
    ss += __shfl_down(ss, off);
    dd += __shfl_down(dd, off);
  }
  if (lane == 0) { as_[wid] = ss; ad_[wid] = dd; }
}

// ---------------- per-node edge softmax + aggregate + bias (+relu), bf16 gather ----------------
// online softmax (1 random sweep) + gather pass unrolled x4 for MLP

template <int VPL>
__global__ __launch_bounds__(256) void agg_kernel(const unsigned short* __restrict__ h,
                                                  const float* __restrict__ as_,
                                                  const float* __restrict__ ad_,
                                                  const int* __restrict__ rowstart,
                                                  const int* __restrict__ csr_src,
                                                  const float* __restrict__ bias,
                                                  float* __restrict__ out,
                                                  int N, int F, int do_relu) {
  int wid = (blockIdx.x * 256 + threadIdx.x) >> 6;
  int lane = threadIdx.x & 63;
  if (wid >= N) return;
  int r0 = rowstart[wid], r1 = rowstart[wid + 1];
  float adn = ad_[wid];

  // fused online-softmax pass: lane-local (m, ssum), then butterfly combine
  float m = -1e30f, ssum = 0.f;
  for (int i = r0 + lane; i < r1; i += 64) {
    float e = leaky(as_[csr_src[i]] + adn);
    float mn = fmaxf(m, e);
    ssum = ssum * __expf(m - mn) + __expf(e - mn);
    m = mn;
  }
#pragma unroll
  for (int off = 32; off; off >>= 1) {
    float mo = __shfl_xor(m, off);
    float so = __shfl_xor(ssum, off);
    float mn = fmaxf(m, mo);
    ssum = ssum * __expf(m - mn) + so * __expf(mo - mn);
    m = mn;
  }
  float inv = 1.f / ssum;

  // gather pass: unroll x4 edges -> 4 row-loads in flight
  const int cbase = lane * VPL;
  float acc[VPL];
#pragma unroll
  for (int v = 0; v < VPL; v++) acc[v] = 0.f;

  int k = r0;
  for (; k + 4 <= r1; k += 4) {
    int s0 = csr_src[k], s1 = csr_src[k + 1], s2 = csr_src[k + 2], s3 = csr_src[k + 3];
    float w0 = __expf(leaky(as_[s0] + adn) - m);
    float w1 = __expf(leaky(as_[s1] + adn) - m);
    float w2 = __expf(leaky(as_[s2] + adn) - m);
    float w3 = __expf(leaky(as_[s3] + adn) - m);
    unsigned short u0[VPL], u1[VPL], u2[VPL], u3[VPL];
    if (VPL == 4) {
      *(ushort4v*)u0 = *(const ushort4v*)(h + (int64_t)s0 * F + cbase);
      *(ushort4v*)u1 = *(const ushort4v*)(h + (int64_t)s1 * F + cbase);
      *(ushort4v*)u2 = *(const ushort4v*)(h + (int64_t)s2 * F + cbase);
      *(ushort4v*)u3 = *(const ushort4v*)(h + (int64_t)s3 * F + cbase);
    } else {
      *(ushort2v*)u0 = *(const ushort2v*)(h + (int64_t)s0 * F + cbase);
      *(ushort2v*)u1 = *(const ushort2v*)(h + (int64_t)s1 * F + cbase);
      *(ushort2v*)u2 = *(const ushort2v*)(h + (int64_t)s2 * F + cbase);
      *(ushort2v*)u3 = *(const ushort2v*)(h + (int64_t)s3 * F + cbase);
    }
#pragma unroll
    for (int v = 0; v < VPL; v++)
      acc[v] += w0 * b2f(u0[v]) + w1 * b2f(u1[v]) + w2 * b2f(u2[v]) + w3 * b2f(u3[v]);
  }
  for (; k < r1; k++) {
    int s = csr_src[k];
    float w = __expf(leaky(as_[s] + adn) - m);
    const unsigned short* hrow = h + (int64_t)s * F + cbase;
    unsigned short uv[VPL];
    if (VPL == 4) *(ushort4v*)uv = *(const ushort4v*)hrow;
    else          *(ushort2v*)uv = *(const ushort2v*)hrow;
#pragma unroll
    for (int v = 0; v < VPL; v++) acc[v] += w * b2f(uv[v]);
  }

  float ov[VPL];
#pragma unroll
  for (int v = 0; v < VPL; v++) {
    float o = acc[v] * inv + bias[cbase + v];
    if (do_relu) o = fmaxf(o, 0.f);
    ov[v] = o;
  }
  float* op = out + (int64_t)wid * F + cbase;
  if (VPL == 4) *(f32x4*)op = *(f32x4*)ov;
  else          *(f32x2*)op = *(f32x2*)ov;
}

// ---------------- layer 3: GEMM (K x 2) + alpha3, wave per row ----------------

__global__ __launch_bounds__(256) void gemm3_kernel(const float* __restrict__ h,
                                                    const float* __restrict__ W3,
                                                    const float* __restrict__ a3s,
                                                    const float* __restrict__ a3d,
                                                    float* __restrict__ h3,
                                                    float* __restrict__ as_,
                                                    float* __restrict__ ad_,
                                                    int N, int K) {
  int wid = (blockIdx.x * 256 + threadIdx.x) >> 6;
  int lane = threadIdx.x & 63;
  if (wid >= N) return;
  float c0 = 0.f, c1 = 0.f;
  for (int k = lane; k < K; k += 64) {
    float v = h[(int64_t)wid * K + k];
    c0 += v * W3[k * 2 + 0];
    c1 += v * W3[k * 2 + 1];
  }
#pragma unroll
  for (int off = 32; off; off >>= 1) {
    c0 += __shfl_down(c0, off);
    c1 += __shfl_down(c1, off);
  }
  if (lane == 0) {
    h3[wid * 2 + 0] = c0;
    h3[wid * 2 + 1] = c1;
    as_[wid] = c0 * a3s[0] + c1 * a3s[1];
    ad_[wid] = c0 * a3d[0] + c1 * a3d[1];
  }
}

// ---------------- layer 3 aggregate + bias + final 2-class softmax ----------------

__global__ __launch_bounds__(256) void agg3_kernel(const float* __restrict__ h3,
                                                   const float* __restrict__ as_,
                                                   const float* __restrict__ ad_,
                                                   const int* __restrict__ rowstart,
                                                   const int* __restrict__ csr_src,
                                                   const float* __restrict__ b3,
                                                   float* __restrict__ out, int N) {
  int wid = (blockIdx.x * 256 + threadIdx.x) >> 6;
  int lane = threadIdx.x & 63;
  if (wid >= N) return;
  int r0 = rowstart[wid], r1 = rowstart[wid + 1];
  float adn = ad_[wid];

  float m = -1e30f;
  for (int i = r0 + lane; i < r1; i += 64) {
    float e = leaky(as_[csr_src[i]] + adn);
    m = fmaxf(m, e);
  }
#pragma unroll
  for (int off = 32; off; off >>= 1) m = fmaxf(m, __shfl_xor(m, off));

  float ssum = 0.f, a0 = 0.f, a1 = 0.f;
  for (int i = r0 + lane; i < r1; i += 64) {
    int s = csr_src[i];
    float e = leaky(as_[s] + adn);
    float w = __expf(e - m);
    ssum += w;
    a0 += w * h3[s * 2 + 0];
    a1 += w * h3[s * 2 + 1];
  }
#pragma unroll
  for (int off = 32; off; off >>= 1) {
    ssum += __shfl_xor(ssum, off);
    a0 += __shfl_xor(a0, off);
    a1 += __shfl_xor(a1, off);
  }
  if (lane == 0) {
    float inv = 1.f / ssum;
    float o0 = a0 * inv + b3[0];
    float o1 = a1 * inv + b3[1];
    float mm = fmaxf(o0, o1);
    float e0 = __expf(o0 - mm), e1 = __expf(o1 - mm);
    float d = e0 + e1;
    out[wid * 2 + 0] = e0 / d;
    out[wid * 2 + 1] = e1 / d;
  }
}

// ---------------- launcher ----------------

extern "C" void kernel_launch(void* const* d_in, const int* in_sizes, int n_in,
                              void* d_out, int out_size, void* d_ws, size_t ws_size,
                              hipStream_t stream) {
  const float* x   = (const float*)d_in[0];
  const int*   ei  = (const int*)d_in[1];
  const float* W1  = (const float*)d_in[3];
  const float* a1s = (const float*)d_in[4];
  const float* a1d = (const float*)d_in[5];
  const float* b1  = (const float*)d_in[6];
  const float* W2  = (const float*)d_in[7];
  const float* a2s = (const float*)d_in[8];
  const float* a2d = (const float*)d_in[9];
  const float* b2  = (const float*)d_in[10];
  const float* W3  = (const float*)d_in[11];
  const float* a3s = (const float*)d_in[12];
  const float* a3d = (const float*)d_in[13];
  const float* b3  = (const float*)d_in[14];

  int N   = in_sizes[2];
  int E   = in_sizes[1] / 2;
  int FIN = in_sizes[0] / N;    // 784
  int d1  = in_sizes[4];        // 128
  int d2  = in_sizes[8];        // 256
  int Kp1 = ((FIN + 31) / 32) * 32;  // 800

  // workspace carve
  char* p = (char*)d_ws;
  unsigned short* hbuf = (unsigned short*)p; p += (size_t)N * d2 * sizeof(float);
  float* buf2 = (float*)p; p += (size_t)N * d2 * sizeof(float);
  float* h3   = (float*)p; p += (size_t)N * 2 * sizeof(float);
  float* as_  = (float*)p; p += (size_t)N * sizeof(float);
  float* ad_  = (float*)p; p += (size_t)N * sizeof(float);
  int* deg      = (int*)p; p += (size_t)N * sizeof(int);
  int* rowstart = (int*)p; p += (size_t)(N + 1) * sizeof(int);
  int* cursor   = (int*)p; p += (size_t)N * sizeof(int);
  int* bsum     = (int*)p; p += 1024 * sizeof(int);
  int* csr      = (int*)p; p += (size_t)(E + N) * sizeof(int);
  p = (char*)(((uintptr_t)p + 255) & ~(uintptr_t)255);
  short* w1h = (short*)p; p += (size_t)d1 * Kp1 * sizeof(short);
  short* w1l = (short*)p; p += (size_t)d1 * Kp1 * sizeof(short);
  short* w2h = (short*)p; p += (size_t)d2 * d1 * sizeof(short);
  short* w2l = (short*)p; p += (size_t)d2 * d1 * sizeof(short);

  // CSR build (multi-block scan; nb<=256 requires N<=262144)
  hipMemsetAsync(deg, 0, (size_t)N * sizeof(int), stream);
  int tot = E + N;
  hist_kernel<<<(tot + 255) / 256, 256, 0, stream>>>(ei, deg, E, N);
  int nb = (N + 1023) / 1024;
  scan_phaseA<<<nb, 256, 0, stream>>>(deg, bsum, N);
  scan_phaseB<<<1, 256, 0, stream>>>(bsum, rowstart, nb, N);
  scan_phaseC<<<nb, 256, 0, stream>>>(deg, bsum, rowstart, cursor, N);
  scatter_kernel<<<(tot + 255) / 256, 256, 0, stream>>>(ei, cursor, csr, E, N);

  // weight transpose+split (tiny)
  convw_kernel<<<(d1 * Kp1 + 255) / 256, 256, 0, stream>>>(W1, w1h, w1l, FIN, d1, Kp1);
  convw_kernel<<<(d2 * d1 + 255) / 256, 256, 0, stream>>>(W2, w2h, w2l, d1, d2, d1);

  int wb = (N + 3) / 4;  // wave-per-node, 4 waves/block

  // layer 1: x@W1 -> hbuf bf16 [N,128]; agg -> buf2 fp32 (relu)
  {
    dim3 g((N + 127) / 128, d1 / 128);
    mfma_gemm_split<<<g, 256, 0, stream>>>(x, w1h, w1l, hbuf, N, d1, FIN, Kp1);
    alpha_kernel<<<wb, 256, 0, stream>>>(hbuf, a1s, a1d, as_, ad_, N, d1);
    agg_kernel<2><<<wb, 256, 0, stream>>>(hbuf, as_, ad_, rowstart, csr, b1, buf2, N, d1, 1);
  }
  // layer 2: buf2@W2 -> hbuf bf16 [N,256]; agg -> buf2 fp32 (relu)
  {
    dim3 g((N + 127) / 128, d2 / 128);
    mfma_gemm_split<<<g, 256, 0, stream>>>(buf2, w2h, w2l, hbuf, N, d2, d1, d1);
    alpha_kernel<<<wb, 256, 0, stream>>>(hbuf, a2s, a2d, as_, ad_, N, d2);
    agg_kernel<4><<<wb, 256, 0, stream>>>(hbuf, as_, ad_, rowstart, csr, b2, buf2, N, d2, 1);
  }
  // layer 3: buf2@W3 -> h3 [N,2]; agg + bias + softmax -> d_out
  {
    gemm3_kernel<<<wb, 256, 0, stream>>>(buf2, W3, a3s, a3d, h3, as_, ad_, N, d2);
    agg3_kernel<<<wb, 256, 0, stream>>>(h3, as_, ad_, rowstart, csr, b3, (float*)d_out, N);
  }
}